// Round 1
// baseline (1339.286 us; speedup 1.0000x reference)
//
#include <hip/hip_runtime.h>
#include <hip/hip_bf16.h>
#include <math.h>

#define NN 100000
#define NR 8
#define NE 1600000
// ED=RD=64, H=4, A=16, D1=32, D2=16

// ---------------- weight prep ----------------
__global__ void k_prep(const float* __restrict__ W_R, const float* __restrict__ W_A,
                       const float* __restrict__ rel, float* __restrict__ W_ra,
                       float* __restrict__ r_emb_a) {
  int tid = blockIdx.x * 256 + threadIdx.x;
  if (tid < NR * 64 * 64) {
    int r = tid >> 12;
    int i = (tid >> 6) & 63;
    int k = tid & 63;
    float acc = 0.f;
    const float* wr = W_R + (r * 64 + i) * 64;
    for (int j = 0; j < 64; ++j) acc += wr[j] * W_A[j * 64 + k];
    W_ra[tid] = acc;
  } else if (tid < NR * 64 * 64 + NR * 64) {
    int idx = tid - NR * 64 * 64;
    int r = idx >> 6, k = idx & 63;
    float acc = 0.f;
    for (int j = 0; j < 64; ++j) acc += rel[r * 64 + j] * W_A[j * 64 + k];
    r_emb_a[idx] = acc;
  }
}

// ---------------- proj: P[r][n][k] = E[n][:] @ W_ra[r][:,k] ----------------
__global__ void k_proj(const float* __restrict__ E, const float* __restrict__ W_ra,
                       float* __restrict__ P) {
  __shared__ float Wl[64 * 64];
  __shared__ float Et[16 * 64];
  int r = blockIdx.y;
  int n0 = blockIdx.x * 16;
  int t = threadIdx.x;
  for (int i = t; i < 4096; i += 256) Wl[i] = W_ra[r * 4096 + i];
  for (int i = t; i < 1024; i += 256) Et[i] = E[n0 * 64 + i];
  __syncthreads();
  int k = t & 63, nr = t >> 6;
  for (int it = 0; it < 4; ++it) {
    int nl = it * 4 + nr;
    float acc = 0.f;
    const float* er = Et + nl * 64;
#pragma unroll
    for (int e = 0; e < 64; ++e) acc += er[e] * Wl[e * 64 + k];
    P[((long)r * NN + n0 + nl) * 64 + k] = acc;
  }
}

// ---------------- CSR build ----------------
__global__ void k_hist(const int* __restrict__ dst, int* __restrict__ cnt) {
  int e = blockIdx.x * 256 + threadIdx.x;
  if (e < NE) atomicAdd(&cnt[dst[e]], 1);
}

#define SCAN_B 1024
#define NSCAN ((NN + SCAN_B - 1) / SCAN_B)  // 98

__global__ void k_scan1(const int* __restrict__ cnt, int* __restrict__ rowp,
                        int* __restrict__ bsum) {
  __shared__ int s[SCAN_B];
  int t = threadIdx.x, g = blockIdx.x * SCAN_B + t;
  s[t] = (g < NN) ? cnt[g] : 0;
  __syncthreads();
  for (int off = 1; off < SCAN_B; off <<= 1) {
    int x = (t >= off) ? s[t - off] : 0;
    __syncthreads();
    s[t] += x;
    __syncthreads();
  }
  if (g < NN) rowp[g + 1] = s[t];
  if (t == SCAN_B - 1) bsum[blockIdx.x] = s[t];
}

__global__ void k_scan2(int* bsum) {
  if (threadIdx.x == 0) {
    int acc = 0;
    for (int i = 0; i < NSCAN; ++i) { int v = bsum[i]; bsum[i] = acc; acc += v; }
  }
}

__global__ void k_scan3(int* rowp, const int* __restrict__ bsum) {
  int t = threadIdx.x, g = blockIdx.x * SCAN_B + t;
  if (g < NN) rowp[g + 1] += bsum[blockIdx.x];
  if (g == 0) rowp[0] = 0;
}

__global__ void k_scatter(const int* __restrict__ src, const int* __restrict__ dst,
                          const int* __restrict__ rowp, int* __restrict__ cur,
                          int* __restrict__ src_sorted, int* __restrict__ epos) {
  int e = blockIdx.x * 256 + threadIdx.x;
  if (e >= NE) return;
  int d = dst[e];
  int p = rowp[d] + atomicAdd(&cur[d], 1);
  src_sorted[p] = src[e];
  epos[e] = p;
}

// ---------------- edge attention logits (one wave per edge) ----------------
__global__ void k_att(const float* __restrict__ P, const float* __restrict__ rea,
                      const int* __restrict__ src, const int* __restrict__ dst,
                      const int* __restrict__ et, const int* __restrict__ epos,
                      float* __restrict__ att) {
  int w = (blockIdx.x * 256 + threadIdx.x) >> 6;
  int lane = threadIdx.x & 63;
  if (w >= NE) return;
  int r = et[w];
  const float* ps = P + ((long)r * NN + src[w]) * 64;
  const float* pd = P + ((long)r * NN + dst[w]) * 64;
  float tt = tanhf(ps[lane]);
  float hh = tanhf(pd[lane] + rea[r * 64 + lane]);
  float prod = tt * hh;
  prod += __shfl_xor(prod, 1);
  prod += __shfl_xor(prod, 2);
  prod += __shfl_xor(prod, 4);
  prod += __shfl_xor(prod, 8);
  if ((lane & 15) == 0) att[epos[w] * 4 + (lane >> 4)] = prod;
}

// ---------------- per-node softmax over incoming edges ----------------
__global__ void k_softmax(const int* __restrict__ rowp, float* __restrict__ att) {
  int n = (blockIdx.x * 256 + threadIdx.x) >> 6;
  int lane = threadIdx.x & 63;
  if (n >= NN) return;
  int p0 = rowp[n] * 4, p1 = rowp[n + 1] * 4;
  float m = -3.4e38f;
  for (int i = p0 + lane; i < p1; i += 64) m = fmaxf(m, att[i]);
  m = fmaxf(m, __shfl_xor(m, 4));
  m = fmaxf(m, __shfl_xor(m, 8));
  m = fmaxf(m, __shfl_xor(m, 16));
  m = fmaxf(m, __shfl_xor(m, 32));
  float z = 0.f;
  for (int i = p0 + lane; i < p1; i += 64) z += expf(att[i] - m);
  z += __shfl_xor(z, 4);
  z += __shfl_xor(z, 8);
  z += __shfl_xor(z, 16);
  z += __shfl_xor(z, 32);
  float inv = 1.f / fmaxf(z, 1e-12f);
  for (int i = p0 + lane; i < p1; i += 64) att[i] = expf(att[i] - m) * inv;
}

// ---------------- message passing, layer 0 (in_dim=64) ----------------
__global__ void k_msg0(const float* __restrict__ ego, const float* __restrict__ att,
                       const int* __restrict__ rowp, const int* __restrict__ srcs,
                       float* __restrict__ NH) {
  int n = (blockIdx.x * 256 + threadIdx.x) >> 6;
  int lane = threadIdx.x & 63;
  if (n >= NN) return;
  int p0 = rowp[n], p1 = rowp[n + 1];
  float a0 = 0, a1 = 0, a2 = 0, a3 = 0;
  for (int p = p0; p < p1; ++p) {
    int s = srcs[p];
    float4 a = ((const float4*)att)[p];
    float ev = ego[s * 64 + lane];
    a0 += ev * a.x; a1 += ev * a.y; a2 += ev * a.z; a3 += ev * a.w;
  }
  float* o = NH + (long)n * 256 + lane;
  o[0] = a0; o[64] = a1; o[128] = a2; o[192] = a3;
}

// ---------------- bi-interaction transform, layer 0 ----------------
__global__ void k_xform0(const float* __restrict__ E, const float* __restrict__ NH,
                         const float* __restrict__ W1, const float* __restrict__ b1,
                         const float* __restrict__ W2, const float* __restrict__ b2,
                         float* __restrict__ out) {
  __shared__ float w1[64 * 8], w2[64 * 8], bb1[8], bb2[8];
  int t = threadIdx.x;
  for (int i = t; i < 512; i += 256) { w1[i] = W1[i]; w2[i] = W2[i]; }
  if (t < 8) { bb1[t] = b1[t]; bb2[t] = b2[t]; }
  __syncthreads();
  int n = blockIdx.x * 8 + (t >> 5);
  int h = (t >> 3) & 3, j = t & 7;
  if (n >= NN) return;
  const float* e = E + n * 64;
  const float* nh = NH + (long)n * 256 + h * 64;
  float s1 = 0.f, s2 = 0.f;
#pragma unroll
  for (int d = 0; d < 64; ++d) {
    float ev = e[d], nv = nh[d];
    s1 += (ev + nv) * w1[d * 8 + j];
    s2 += (ev * nv) * w2[d * 8 + j];
  }
  s1 += bb1[j]; s2 += bb2[j];
  s1 = (s1 >= 0.f) ? s1 : 0.01f * s1;
  s2 = (s2 >= 0.f) ? s2 : 0.01f * s2;
  out[n * 32 + h * 8 + j] = s1 + s2;
}

// ---------------- message passing, layer 1 (in_dim=32) ----------------
__global__ void k_msg1(const float* __restrict__ ego1, const float* __restrict__ att,
                       const int* __restrict__ rowp, const int* __restrict__ srcs,
                       float* __restrict__ NH) {
  int n = (blockIdx.x * 256 + threadIdx.x) >> 6;
  int lane = threadIdx.x & 63;
  if (n >= NN) return;
  int d = lane & 31;
  bool up = lane >= 32;
  int p0 = rowp[n], p1 = rowp[n + 1];
  float aa = 0, ab = 0;
  for (int p = p0; p < p1; ++p) {
    int s = srcs[p];
    float4 a = ((const float4*)att)[p];
    float ev = ego1[s * 32 + d];
    float alo = up ? a.z : a.x;
    float ahi = up ? a.w : a.y;
    aa += ev * alo; ab += ev * ahi;
  }
  float* o = NH + (long)n * 128 + (up ? 64 : 0) + d;
  o[0] = aa; o[32] = ab;
}

// ---------------- bi-interaction transform, layer 1 ----------------
__global__ void k_xform1(const float* __restrict__ E1, const float* __restrict__ NH,
                         const float* __restrict__ W1, const float* __restrict__ b1,
                         const float* __restrict__ W2, const float* __restrict__ b2,
                         float* __restrict__ out) {
  __shared__ float w1[32 * 4], w2[32 * 4];
  int t = threadIdx.x;
  if (t < 128) w1[t] = W1[t];
  else if (t < 256) w2[t - 128] = W2[t - 128];
  __syncthreads();
  int n = blockIdx.x * 16 + (t >> 4);
  int h = (t >> 2) & 3, j = t & 3;
  if (n >= NN) return;
  const float* e = E1 + n * 32;
  const float* nh = NH + (long)n * 128 + h * 32;
  float s1 = 0.f, s2 = 0.f;
#pragma unroll
  for (int d = 0; d < 32; ++d) {
    float ev = e[d], nv = nh[d];
    s1 += (ev + nv) * w1[d * 4 + j];
    s2 += (ev * nv) * w2[d * 4 + j];
  }
  s1 += b1[j]; s2 += b2[j];
  s1 = (s1 >= 0.f) ? s1 : 0.01f * s1;
  s2 = (s2 >= 0.f) ? s2 : 0.01f * s2;
  out[n * 16 + h * 4 + j] = s1 + s2;
}

// ---------------- gather user/item rows with l2norm into U, V ----------------
__global__ void k_uv(const float* __restrict__ E, const float* __restrict__ E1,
                     const float* __restrict__ E2, const int* __restrict__ uid,
                     const int* __restrict__ iid, float* __restrict__ U,
                     float* __restrict__ V) {
  int row = (blockIdx.x * 256 + threadIdx.x) >> 6;
  int lane = threadIdx.x & 63;
  if (row >= 1000 + 4096) return;
  int id = (row < 1000) ? uid[row] : iid[row - 1000];
  float* dest = (row < 1000) ? (U + row * 112) : (V + (row - 1000) * 112);
  float v1 = (lane < 32) ? E1[id * 32 + lane] : 0.f;
  float s1 = v1 * v1;
  for (int m = 1; m < 64; m <<= 1) s1 += __shfl_xor(s1, m);
  float v2 = (lane < 16) ? E2[id * 16 + lane] : 0.f;
  float s2 = v2 * v2;
  for (int m = 1; m < 64; m <<= 1) s2 += __shfl_xor(s2, m);
  float i1 = 1.f / fmaxf(sqrtf(s1), 1e-12f);
  float i2 = 1.f / fmaxf(sqrtf(s2), 1e-12f);
  dest[lane] = E[id * 64 + lane];
  if (lane < 32) dest[64 + lane] = v1 * i1;
  if (lane < 16) dest[96 + lane] = v2 * i2;
}

// ---------------- final small GEMM: C[1000,4096] = U @ V^T (K=112) ----------------
__global__ void k_gemm(const float* __restrict__ U, const float* __restrict__ V,
                       float* __restrict__ C) {
  __shared__ float Us[16][113], Vs[16][113];
  int tx = threadIdx.x & 15, ty = threadIdx.x >> 4;
  int u0 = blockIdx.y * 16, v0 = blockIdx.x * 16;
  for (int i = threadIdx.x; i < 16 * 112; i += 256) {
    int rr = i / 112, cc = i % 112;
    int ur = u0 + rr;
    Us[rr][cc] = (ur < 1000) ? U[ur * 112 + cc] : 0.f;
    Vs[rr][cc] = V[(v0 + rr) * 112 + cc];
  }
  __syncthreads();
  int u = u0 + ty;
  if (u >= 1000) return;
  float acc = 0.f;
#pragma unroll
  for (int k = 0; k < 112; ++k) acc += Us[ty][k] * Vs[tx][k];
  C[u * 4096 + v0 + tx] = acc;
}

extern "C" void kernel_launch(void* const* d_in, const int* in_sizes, int n_in,
                              void* d_out, int out_size, void* d_ws, size_t ws_size,
                              hipStream_t stream) {
  const int* src = (const int*)d_in[0];
  const int* dst = (const int*)d_in[1];
  const int* etype = (const int*)d_in[2];
  const int* uid = (const int*)d_in[4];
  const int* iid = (const int*)d_in[5];
  const float* entity = (const float*)d_in[6];
  const float* rel = (const float*)d_in[7];
  const float* W_R = (const float*)d_in[8];
  const float* W_A = (const float*)d_in[9];
  const float* W1_0 = (const float*)d_in[10];
  const float* b1_0 = (const float*)d_in[11];
  const float* W2_0 = (const float*)d_in[12];
  const float* b2_0 = (const float*)d_in[13];
  const float* W1_1 = (const float*)d_in[14];
  const float* b1_1 = (const float*)d_in[15];
  const float* W2_1 = (const float*)d_in[16];
  const float* b2_1 = (const float*)d_in[17];
  float* out = (float*)d_out;

  char* ws = (char*)d_ws;
  // workspace layout (bytes)
  float* P     = (float*)(ws + 0);              // 204,800,000  (dead after k_att)
  float* NH0   = (float*)(ws + 0);              // 102,400,000  (aliases P)
  float* NH1   = (float*)(ws + 102400000);      //  51,200,000  (aliases P)
  float* att   = (float*)(ws + 204800000);      //  25,600,000
  int*   srcs  = (int*)  (ws + 230400000);      //   6,400,000
  int*   epos  = (int*)  (ws + 236800000);      //   6,400,000
  int*   rowp  = (int*)  (ws + 243200000);      //     400,128
  int*   cnt   = (int*)  (ws + 243600128);      //     400,128
  int*   bsum  = (int*)  (ws + 244000256);      //         512
  float* W_ra  = (float*)(ws + 244000768);      //     131,072
  float* rea   = (float*)(ws + 244131840);      //       2,048
  float* ego1  = (float*)(ws + 244133888);      //  12,800,000
  float* ego2  = (float*)(ws + 256933888);      //   6,400,000
  float* U     = (float*)(ws + 263333888);      //     448,000
  float* V     = (float*)(ws + 263781888);      //   1,835,008
  // total: 265,616,896 bytes

  hipMemsetAsync(cnt, 0, NN * sizeof(int), stream);
  k_prep<<<130, 256, 0, stream>>>(W_R, W_A, rel, W_ra, rea);
  k_proj<<<dim3(NN / 16, NR), 256, 0, stream>>>(entity, W_ra, P);
  k_hist<<<NE / 256, 256, 0, stream>>>(dst, cnt);
  k_scan1<<<NSCAN, SCAN_B, 0, stream>>>(cnt, rowp, bsum);
  k_scan2<<<1, 64, 0, stream>>>(bsum);
  k_scan3<<<NSCAN, SCAN_B, 0, stream>>>(rowp, bsum);
  hipMemsetAsync(cnt, 0, NN * sizeof(int), stream);
  k_scatter<<<NE / 256, 256, 0, stream>>>(src, dst, rowp, cnt, srcs, epos);
  k_att<<<NE / 4, 256, 0, stream>>>(P, rea, src, dst, etype, epos, att);
  k_softmax<<<NN / 4, 256, 0, stream>>>(rowp, att);
  k_msg0<<<NN / 4, 256, 0, stream>>>(entity, att, rowp, srcs, NH0);
  k_xform0<<<NN / 8, 256, 0, stream>>>(entity, NH0, W1_0, b1_0, W2_0, b2_0, ego1);
  k_msg1<<<NN / 4, 256, 0, stream>>>(ego1, att, rowp, srcs, NH1);
  k_xform1<<<NN / 16, 256, 0, stream>>>(ego1, NH1, W1_1, b1_1, W2_1, b2_1, ego2);
  k_uv<<<(1000 + 4096 + 3) / 4, 256, 0, stream>>>(entity, ego1, ego2, uid, iid, U, V);
  k_gemm<<<dim3(4096 / 16, (1000 + 15) / 16), 256, 0, stream>>>(U, V, out);
}

// Round 2
// 1223.136 us; speedup vs baseline: 1.0950x; 1.0950x over previous
//
#include <hip/hip_runtime.h>
#include <hip/hip_bf16.h>
#include <math.h>

#define NN 100000
#define NR 8
#define NE 1600000
// ED=RD=64, H=4, A=16, D1=32, D2=16

__device__ inline float bf2f(unsigned short u) {
  union { unsigned int i; float f; } v; v.i = ((unsigned int)u) << 16; return v.f;
}
__device__ inline unsigned short f2bf(float f) {
  __hip_bfloat16 h = __float2bfloat16(f);
  return *reinterpret_cast<unsigned short*>(&h);
}

// ---------------- weight prep ----------------
__global__ void k_prep(const float* __restrict__ W_R, const float* __restrict__ W_A,
                       const float* __restrict__ rel, float* __restrict__ W_ra,
                       float* __restrict__ r_emb_a) {
  int tid = blockIdx.x * 256 + threadIdx.x;
  if (tid < NR * 64 * 64) {
    int r = tid >> 12;
    int i = (tid >> 6) & 63;
    int k = tid & 63;
    float acc = 0.f;
    const float* wr = W_R + (r * 64 + i) * 64;
    for (int j = 0; j < 64; ++j) acc += wr[j] * W_A[j * 64 + k];
    W_ra[tid] = acc;
  } else if (tid < NR * 64 * 64 + NR * 64) {
    int idx = tid - NR * 64 * 64;
    int r = idx >> 6, k = idx & 63;
    float acc = 0.f;
    for (int j = 0; j < 64; ++j) acc += rel[r * 64 + j] * W_A[j * 64 + k];
    r_emb_a[idx] = acc;
  }
}

// ---------------- entity -> bf16 copy ----------------
__global__ void k_cvt(const float* __restrict__ E, unsigned short* __restrict__ Ebf) {
  int i = blockIdx.x * 256 + threadIdx.x;  // handles 4 floats
  float4 v = ((const float4*)E)[i];
  ushort4 o;
  o.x = f2bf(v.x); o.y = f2bf(v.y); o.z = f2bf(v.z); o.w = f2bf(v.w);
  ((ushort4*)Ebf)[i] = o;
}

// ---------------- proj + tanh: T1/T2[r][n][k] bf16 ----------------
__global__ void k_proj(const float* __restrict__ E, const float* __restrict__ W_ra,
                       const float* __restrict__ rea,
                       unsigned short* __restrict__ T1, unsigned short* __restrict__ T2) {
  __shared__ float Wl[64 * 64];
  __shared__ float Et[16 * 64];
  int r = blockIdx.y;
  int n0 = blockIdx.x * 16;
  int t = threadIdx.x;
  for (int i = t; i < 4096; i += 256) Wl[i] = W_ra[r * 4096 + i];
  for (int i = t; i < 1024; i += 256) Et[i] = E[n0 * 64 + i];
  __syncthreads();
  int k = t & 63, nr = t >> 6;
  float rk = rea[r * 64 + k];
  for (int it = 0; it < 4; ++it) {
    int nl = it * 4 + nr;
    float acc = 0.f;
    const float* er = Et + nl * 64;
#pragma unroll
    for (int e = 0; e < 64; ++e) acc += er[e] * Wl[e * 64 + k];
    long idx = ((long)r * NN + n0 + nl) * 64 + k;
    T1[idx] = f2bf(tanhf(acc));
    T2[idx] = f2bf(tanhf(acc + rk));
  }
}

// ---------------- CSR build ----------------
__global__ void k_hist(const int* __restrict__ dst, int* __restrict__ cnt) {
  int e = blockIdx.x * 256 + threadIdx.x;
  if (e < NE) atomicAdd(&cnt[dst[e]], 1);
}

#define SCAN_B 1024
#define NSCAN ((NN + SCAN_B - 1) / SCAN_B)  // 98

__global__ void k_scan1(const int* __restrict__ cnt, int* __restrict__ rowp,
                        int* __restrict__ bsum) {
  __shared__ int s[SCAN_B];
  int t = threadIdx.x, g = blockIdx.x * SCAN_B + t;
  s[t] = (g < NN) ? cnt[g] : 0;
  __syncthreads();
  for (int off = 1; off < SCAN_B; off <<= 1) {
    int x = (t >= off) ? s[t - off] : 0;
    __syncthreads();
    s[t] += x;
    __syncthreads();
  }
  if (g < NN) rowp[g + 1] = s[t];
  if (t == SCAN_B - 1) bsum[blockIdx.x] = s[t];
}

__global__ void k_scan2(int* bsum) {
  if (threadIdx.x == 0) {
    int acc = 0;
    for (int i = 0; i < NSCAN; ++i) { int v = bsum[i]; bsum[i] = acc; acc += v; }
  }
}

__global__ void k_scan3(int* rowp, const int* __restrict__ bsum) {
  int t = threadIdx.x, g = blockIdx.x * SCAN_B + t;
  if (g < NN) rowp[g + 1] += bsum[blockIdx.x];
  if (g == 0) rowp[0] = 0;
}

__global__ void k_scatter(const int* __restrict__ src, const int* __restrict__ dst,
                          const int* __restrict__ etype, const int* __restrict__ rowp,
                          int* __restrict__ cur, int* __restrict__ srcs,
                          int* __restrict__ ets, int* __restrict__ dsts) {
  int e = blockIdx.x * 256 + threadIdx.x;
  if (e >= NE) return;
  int d = dst[e];
  int p = rowp[d] + atomicAdd(&cur[d], 1);
  srcs[p] = src[e];
  ets[p] = etype[e];
  dsts[p] = d;
}

// ---------------- edge attention logits (sorted order, bf16 gather) ----------------
__global__ void k_att(const unsigned short* __restrict__ T1,
                      const unsigned short* __restrict__ T2,
                      const int* __restrict__ srcs, const int* __restrict__ dsts,
                      const int* __restrict__ ets, float* __restrict__ att) {
  int e = (blockIdx.x * 256 + threadIdx.x) >> 6;
  int lane = threadIdx.x & 63;
  if (e >= NE) return;
  int r = ets[e], s = srcs[e], d = dsts[e];
  float a = bf2f(T1[((long)r * NN + s) * 64 + lane]);
  float b = bf2f(T2[((long)r * NN + d) * 64 + lane]);
  float prod = a * b;
  prod += __shfl_xor(prod, 1);
  prod += __shfl_xor(prod, 2);
  prod += __shfl_xor(prod, 4);
  prod += __shfl_xor(prod, 8);
  float hv = __shfl(prod, (lane & 3) << 4);
  if (lane < 4) att[e * 4 + lane] = hv;
}

// ---------------- fused softmax + message + bi-transform, layer 0 ----------------
__global__ void k_fused0(const float* __restrict__ E, const unsigned short* __restrict__ Ebf,
                         const float* __restrict__ att, float* __restrict__ attn,
                         const int* __restrict__ rowp, const int* __restrict__ srcs,
                         const float* __restrict__ W1, const float* __restrict__ b1,
                         const float* __restrict__ W2, const float* __restrict__ b2,
                         float* __restrict__ ego1, unsigned short* __restrict__ ego1bf) {
  __shared__ float w1[512], w2[512], bb[16];
  __shared__ float s1[4][4][68], s2[4][4][68];
  int t = threadIdx.x;
  for (int i = t; i < 512; i += 256) { w1[i] = W1[i]; w2[i] = W2[i]; }
  if (t < 8) bb[t] = b1[t];
  else if (t < 16) bb[t] = b2[t - 8];
  __syncthreads();
  int wv = t >> 6, lane = t & 63;
  int n = blockIdx.x * 4 + wv;
  int p0 = rowp[n], p1 = rowp[n + 1];
  float ed = E[n * 64 + lane];
  // pass 1: per-head max (head class = lane&3)
  float m = -3.4e38f;
  for (int i = p0 * 4 + lane; i < p1 * 4; i += 64) m = fmaxf(m, att[i]);
  m = fmaxf(m, __shfl_xor(m, 4));
  m = fmaxf(m, __shfl_xor(m, 8));
  m = fmaxf(m, __shfl_xor(m, 16));
  m = fmaxf(m, __shfl_xor(m, 32));
  // pass 2: denom
  float z = 0.f;
  for (int i = p0 * 4 + lane; i < p1 * 4; i += 64) z += __expf(att[i] - m);
  z += __shfl_xor(z, 4);
  z += __shfl_xor(z, 8);
  z += __shfl_xor(z, 16);
  z += __shfl_xor(z, 32);
  float inv = 1.f / fmaxf(z, 1e-12f);
  // broadcast per-head m, inv (lanes 0..3 hold heads 0..3)
  float m0 = __shfl(m, 0), m1 = __shfl(m, 1), m2 = __shfl(m, 2), m3 = __shfl(m, 3);
  float i0 = __shfl(inv, 0), i1 = __shfl(inv, 1), i2 = __shfl(inv, 2), i3 = __shfl(inv, 3);
  // pass 3: accumulate messages with in-register normalization (reads RAW att only)
  float a0 = 0.f, a1 = 0.f, a2 = 0.f, a3 = 0.f;
  for (int p = p0; p < p1; ++p) {
    int s = srcs[p];
    float4 a = ((const float4*)att)[p];
    float ax = __expf(a.x - m0) * i0;
    float ay = __expf(a.y - m1) * i1;
    float az = __expf(a.z - m2) * i2;
    float aw = __expf(a.w - m3) * i3;
    float ev = bf2f(Ebf[s * 64 + lane]);
    a0 += ev * ax; a1 += ev * ay; a2 += ev * az; a3 += ev * aw;
  }
  // pass 4: write normalized attention for layer-1 kernel (separate buffer)
  for (int i = p0 * 4 + lane; i < p1 * 4; i += 64) attn[i] = __expf(att[i] - m) * inv;
  // transform
  s1[wv][0][lane] = ed + a0; s2[wv][0][lane] = ed * a0;
  s1[wv][1][lane] = ed + a1; s2[wv][1][lane] = ed * a1;
  s1[wv][2][lane] = ed + a2; s2[wv][2][lane] = ed * a2;
  s1[wv][3][lane] = ed + a3; s2[wv][3][lane] = ed * a3;
  __syncthreads();
  int h = (lane >> 3) & 3, j = lane & 7;
  const float* sp = (lane < 32) ? &s1[wv][h][0] : &s2[wv][h][0];
  const float* wp = (lane < 32) ? w1 : w2;
  float p = 0.f;
#pragma unroll
  for (int d = 0; d < 64; ++d) p += sp[d] * wp[d * 8 + j];
  p += (lane < 32) ? bb[j] : bb[8 + j];
  p = (p >= 0.f) ? p : 0.01f * p;
  float other = __shfl_xor(p, 32);
  if (lane < 32) {
    float o = p + other;
    ego1[n * 32 + h * 8 + j] = o;
    ego1bf[n * 32 + h * 8 + j] = f2bf(o);
  }
}

// ---------------- fused message + bi-transform, layer 1 ----------------
__global__ void k_fused1(const float* __restrict__ ego1, const unsigned short* __restrict__ E1bf,
                         const float* __restrict__ attn,
                         const int* __restrict__ rowp, const int* __restrict__ srcs,
                         const float* __restrict__ W1, const float* __restrict__ b1,
                         const float* __restrict__ W2, const float* __restrict__ b2,
                         float* __restrict__ ego2) {
  __shared__ float w1[128], w2[128], bb[8];
  __shared__ float s1[4][4][36], s2[4][4][36];
  int t = threadIdx.x;
  if (t < 128) w1[t] = W1[t];
  else if (t < 256) w2[t - 128] = W2[t - 128];
  if (t < 4) bb[t] = b1[t];
  else if (t < 8) bb[t] = b2[t - 4];
  __syncthreads();
  int wv = t >> 6, lane = t & 63;
  int n = blockIdx.x * 4 + wv;
  int d = lane & 31;
  bool up = lane >= 32;
  int p0 = rowp[n], p1 = rowp[n + 1];
  float aa = 0.f, ab = 0.f;
  for (int p = p0; p < p1; ++p) {
    int s = srcs[p];
    float4 a = ((const float4*)attn)[p];
    float ev = bf2f(E1bf[s * 32 + d]);
    float alo = up ? a.z : a.x;
    float ahi = up ? a.w : a.y;
    aa += ev * alo; ab += ev * ahi;
  }
  float e1 = ego1[n * 32 + d];
  int h0 = up ? 2 : 0, h1 = up ? 3 : 1;
  s1[wv][h0][d] = e1 + aa; s2[wv][h0][d] = e1 * aa;
  s1[wv][h1][d] = e1 + ab; s2[wv][h1][d] = e1 * ab;
  __syncthreads();
  if (lane < 32) {
    int h = (lane >> 2) & 3, j = lane & 3;
    const float* sp = (lane < 16) ? &s1[wv][h][0] : &s2[wv][h][0];
    const float* wp = (lane < 16) ? w1 : w2;
    float p = 0.f;
#pragma unroll
    for (int dd = 0; dd < 32; ++dd) p += sp[dd] * wp[dd * 4 + j];
    p += (lane < 16) ? bb[j] : bb[4 + j];
    p = (p >= 0.f) ? p : 0.01f * p;
    float other = __shfl_xor(p, 16);
    if (lane < 16) ego2[n * 16 + lane] = p + other;
  }
}

// ---------------- gather user/item rows with l2norm into U, V ----------------
__global__ void k_uv(const float* __restrict__ E, const float* __restrict__ E1,
                     const float* __restrict__ E2, const int* __restrict__ uid,
                     const int* __restrict__ iid, float* __restrict__ U,
                     float* __restrict__ V) {
  int row = (blockIdx.x * 256 + threadIdx.x) >> 6;
  int lane = threadIdx.x & 63;
  if (row >= 1000 + 4096) return;
  int id = (row < 1000) ? uid[row] : iid[row - 1000];
  float* dest = (row < 1000) ? (U + row * 112) : (V + (row - 1000) * 112);
  float v1 = (lane < 32) ? E1[id * 32 + lane] : 0.f;
  float s1 = v1 * v1;
  for (int m = 1; m < 64; m <<= 1) s1 += __shfl_xor(s1, m);
  float v2 = (lane < 16) ? E2[id * 16 + lane] : 0.f;
  float s2 = v2 * v2;
  for (int m = 1; m < 64; m <<= 1) s2 += __shfl_xor(s2, m);
  float i1 = 1.f / fmaxf(sqrtf(s1), 1e-12f);
  float i2 = 1.f / fmaxf(sqrtf(s2), 1e-12f);
  dest[lane] = E[id * 64 + lane];
  if (lane < 32) dest[64 + lane] = v1 * i1;
  if (lane < 16) dest[96 + lane] = v2 * i2;
}

// ---------------- final small GEMM: C[1000,4096] = U @ V^T (K=112) ----------------
__global__ void k_gemm(const float* __restrict__ U, const float* __restrict__ V,
                       float* __restrict__ C) {
  __shared__ float Us[16][113], Vs[16][113];
  int tx = threadIdx.x & 15, ty = threadIdx.x >> 4;
  int u0 = blockIdx.y * 16, v0 = blockIdx.x * 16;
  for (int i = threadIdx.x; i < 16 * 112; i += 256) {
    int rr = i / 112, cc = i % 112;
    int ur = u0 + rr;
    Us[rr][cc] = (ur < 1000) ? U[ur * 112 + cc] : 0.f;
    Vs[rr][cc] = V[(v0 + rr) * 112 + cc];
  }
  __syncthreads();
  int u = u0 + ty;
  if (u >= 1000) return;
  float acc = 0.f;
#pragma unroll
  for (int k = 0; k < 112; ++k) acc += Us[ty][k] * Vs[tx][k];
  C[u * 4096 + v0 + tx] = acc;
}

extern "C" void kernel_launch(void* const* d_in, const int* in_sizes, int n_in,
                              void* d_out, int out_size, void* d_ws, size_t ws_size,
                              hipStream_t stream) {
  const int* src = (const int*)d_in[0];
  const int* dst = (const int*)d_in[1];
  const int* etype = (const int*)d_in[2];
  const int* uid = (const int*)d_in[4];
  const int* iid = (const int*)d_in[5];
  const float* entity = (const float*)d_in[6];
  const float* rel = (const float*)d_in[7];
  const float* W_R = (const float*)d_in[8];
  const float* W_A = (const float*)d_in[9];
  const float* W1_0 = (const float*)d_in[10];
  const float* b1_0 = (const float*)d_in[11];
  const float* W2_0 = (const float*)d_in[12];
  const float* b2_0 = (const float*)d_in[13];
  const float* W1_1 = (const float*)d_in[14];
  const float* b1_1 = (const float*)d_in[15];
  const float* W2_1 = (const float*)d_in[16];
  const float* b2_1 = (const float*)d_in[17];
  float* out = (float*)d_out;

  char* ws = (char*)d_ws;
  // workspace layout (bytes); T1 region is reused after k_att for layer outputs,
  // T2 region is reused for normalized attention.
  unsigned short* T1   = (unsigned short*)(ws + 0);            // 102,400,000
  float*          ego1 = (float*)         (ws + 0);            //  12,800,000 (alias T1)
  unsigned short* e1bf = (unsigned short*)(ws + 12800000);     //   6,400,000 (alias T1)
  float*          ego2 = (float*)         (ws + 19200000);     //   6,400,000 (alias T1)
  float*          U    = (float*)         (ws + 25600000);     //     448,000 (alias T1)
  float*          V    = (float*)         (ws + 26048000);     //   1,835,008 (alias T1)
  unsigned short* T2   = (unsigned short*)(ws + 102400000);    // 102,400,000
  float*          attn = (float*)         (ws + 102400000);    //  25,600,000 (alias T2)
  float*          att  = (float*)         (ws + 204800000);    //  25,600,000
  int*            srcs = (int*)           (ws + 230400000);    //   6,400,000
  int*            ets  = (int*)           (ws + 236800000);    //   6,400,000
  int*            dsts = (int*)           (ws + 243200000);    //   6,400,000
  int*            rowp = (int*)           (ws + 249600000);    //     400,128
  int*            cnt  = (int*)           (ws + 250000128);    //     400,128
  int*            bsum = (int*)           (ws + 250400256);    //         512
  float*          W_ra = (float*)         (ws + 250400768);    //     131,072
  float*          rea  = (float*)         (ws + 250531840);    //       2,048
  unsigned short* Ebf  = (unsigned short*)(ws + 250533888);    //  12,800,000
  // total: 263,333,888 bytes

  hipMemsetAsync(cnt, 0, NN * sizeof(int), stream);
  k_prep<<<130, 256, 0, stream>>>(W_R, W_A, rel, W_ra, rea);
  k_cvt<<<6250, 256, 0, stream>>>(entity, Ebf);
  k_proj<<<dim3(NN / 16, NR), 256, 0, stream>>>(entity, W_ra, rea, T1, T2);
  k_hist<<<NE / 256, 256, 0, stream>>>(dst, cnt);
  k_scan1<<<NSCAN, SCAN_B, 0, stream>>>(cnt, rowp, bsum);
  k_scan2<<<1, 64, 0, stream>>>(bsum);
  k_scan3<<<NSCAN, SCAN_B, 0, stream>>>(rowp, bsum);
  hipMemsetAsync(cnt, 0, NN * sizeof(int), stream);
  k_scatter<<<NE / 256, 256, 0, stream>>>(src, dst, etype, rowp, cnt, srcs, ets, dsts);
  k_att<<<NE / 4, 256, 0, stream>>>(T1, T2, srcs, dsts, ets, att);
  k_fused0<<<NN / 4, 256, 0, stream>>>(entity, Ebf, att, attn, rowp, srcs,
                                       W1_0, b1_0, W2_0, b2_0, ego1, e1bf);
  k_fused1<<<NN / 4, 256, 0, stream>>>(ego1, e1bf, attn, rowp, srcs,
                                       W1_1, b1_1, W2_1, b2_1, ego2);
  k_uv<<<(1000 + 4096 + 3) / 4, 256, 0, stream>>>(entity, ego1, ego2, uid, iid, U, V);
  k_gemm<<<dim3(4096 / 16, (1000 + 15) / 16), 256, 0, stream>>>(U, V, out);
}

// Round 3
// 1023.322 us; speedup vs baseline: 1.3088x; 1.1953x over previous
//
#include <hip/hip_runtime.h>
#include <hip/hip_bf16.h>
#include <math.h>

#define NN 100000
#define NR 8
#define NE 1600000
// ED=RD=64, H=4, A=16, D1=32, D2=16

typedef __attribute__((ext_vector_type(8))) short short8v;
typedef __attribute__((ext_vector_type(4))) float float4v;

__device__ inline float bf2f(unsigned short u) {
  union { unsigned int i; float f; } v; v.i = ((unsigned int)u) << 16; return v.f;
}
__device__ inline unsigned short f2bf(float f) {
  __hip_bfloat16 h = __float2bfloat16(f);
  return *reinterpret_cast<unsigned short*>(&h);
}
__device__ inline float fast_tanh(float x) {
  float ex = __expf(2.f * x);
  return 1.f - 2.f * __builtin_amdgcn_rcpf(ex + 1.f);
}

// ---------------- weight prep: Wbf[c][e] bf16 col-major, rea[512] ----------------
__global__ void k_prep(const float* __restrict__ W_R, const float* __restrict__ W_A,
                       const float* __restrict__ rel, unsigned short* __restrict__ Wbf,
                       float* __restrict__ r_emb_a) {
  int tid = blockIdx.x * 256 + threadIdx.x;
  if (tid < NR * 64 * 64) {
    int r = tid >> 12;
    int i = (tid >> 6) & 63;   // embed dim e
    int k = tid & 63;          // output dim within relation
    float acc = 0.f;
    const float* wr = W_R + (r * 64 + i) * 64;
    for (int j = 0; j < 64; ++j) acc += wr[j] * W_A[j * 64 + k];
    Wbf[(r * 64 + k) * 64 + i] = f2bf(acc);   // col-major: [c=r*64+k][e=i]
  } else if (tid < NR * 64 * 64 + NR * 64) {
    int idx = tid - NR * 64 * 64;
    int r = idx >> 6, k = idx & 63;
    float acc = 0.f;
    for (int j = 0; j < 64; ++j) acc += rel[r * 64 + j] * W_A[j * 64 + k];
    r_emb_a[idx] = acc;
  }
}

// ---------------- entity -> bf16 copy ----------------
__global__ void k_cvt(const float* __restrict__ E, unsigned short* __restrict__ Ebf) {
  int i = blockIdx.x * 256 + threadIdx.x;  // handles 4 floats
  float4 v = ((const float4*)E)[i];
  ushort4 o;
  o.x = f2bf(v.x); o.y = f2bf(v.y); o.z = f2bf(v.z); o.w = f2bf(v.w);
  ((ushort4*)Ebf)[i] = o;
}

// ---------------- proj via MFMA: T1/T2[r][n][k] = tanh(E@W_ra (+rea)) bf16 ----------------
// Block = 64 nodes (4 waves x 16). Wave computes its 16 nodes x all 512 cols.
__global__ void k_proj(const unsigned short* __restrict__ Ebf,
                       const unsigned short* __restrict__ Wbf,
                       const float* __restrict__ rea,
                       unsigned short* __restrict__ T1, unsigned short* __restrict__ T2) {
  int wv = threadIdx.x >> 6, lane = threadIdx.x & 63;
  int n0 = blockIdx.x * 64 + wv * 16;
  int mrow = lane & 15, kg = lane >> 4;  // kg in 0..3
  // A-frag: lane holds E[node=n0+mrow][k = t*32 + kg*8 + 0..7] for mfma t=0,1
  int nodeA = n0 + mrow;
  if (nodeA >= NN) nodeA = NN - 1;
  const short8v a0 = *(const short8v*)(Ebf + (long)nodeA * 64 + kg * 8);
  const short8v a1 = *(const short8v*)(Ebf + (long)nodeA * 64 + 32 + kg * 8);
  int orow = kg * 4;  // output row group for this lane
  for (int ct = 0; ct < 32; ++ct) {
    int c = ct * 16 + mrow;  // global output column 0..511
    const short8v b0 = *(const short8v*)(Wbf + c * 64 + kg * 8);
    const short8v b1 = *(const short8v*)(Wbf + c * 64 + 32 + kg * 8);
    float4v acc = {0.f, 0.f, 0.f, 0.f};
    acc = __builtin_amdgcn_mfma_f32_16x16x32_bf16(a0, b0, acc, 0, 0, 0);
    acc = __builtin_amdgcn_mfma_f32_16x16x32_bf16(a1, b1, acc, 0, 0, 0);
    float rv = rea[c];
    int r = c >> 6, kk = c & 63;
#pragma unroll
    for (int i = 0; i < 4; ++i) {
      int nd = n0 + orow + i;
      if (nd < NN) {
        long base = ((long)r * NN + nd) * 64 + kk;
        T1[base] = f2bf(fast_tanh(acc[i]));
        T2[base] = f2bf(fast_tanh(acc[i] + rv));
      }
    }
  }
}

// ---------------- CSR build ----------------
__global__ void k_hist(const int* __restrict__ dst, int* __restrict__ cnt) {
  int e = blockIdx.x * 256 + threadIdx.x;
  if (e < NE) atomicAdd(&cnt[dst[e]], 1);
}

#define SCAN_B 1024
#define NSCAN ((NN + SCAN_B - 1) / SCAN_B)  // 98

__global__ void k_scan1(const int* __restrict__ cnt, int* __restrict__ rowp,
                        int* __restrict__ bsum) {
  __shared__ int s[SCAN_B];
  int t = threadIdx.x, g = blockIdx.x * SCAN_B + t;
  s[t] = (g < NN) ? cnt[g] : 0;
  __syncthreads();
  for (int off = 1; off < SCAN_B; off <<= 1) {
    int x = (t >= off) ? s[t - off] : 0;
    __syncthreads();
    s[t] += x;
    __syncthreads();
  }
  if (g < NN) rowp[g + 1] = s[t];
  if (t == SCAN_B - 1) bsum[blockIdx.x] = s[t];
}

__global__ void k_scan2(int* bsum) {
  if (threadIdx.x == 0) {
    int acc = 0;
    for (int i = 0; i < NSCAN; ++i) { int v = bsum[i]; bsum[i] = acc; acc += v; }
  }
}

__global__ void k_scan3(int* rowp, const int* __restrict__ bsum) {
  int t = threadIdx.x, g = blockIdx.x * SCAN_B + t;
  if (g < NN) rowp[g + 1] += bsum[blockIdx.x];
  if (g == 0) rowp[0] = 0;
}

__global__ void k_scatter(const int* __restrict__ src, const int* __restrict__ dst,
                          const int* __restrict__ etype, const int* __restrict__ rowp,
                          int* __restrict__ cur, int* __restrict__ srcs,
                          int* __restrict__ ets, int* __restrict__ dsts) {
  int e = blockIdx.x * 256 + threadIdx.x;
  if (e >= NE) return;
  int d = dst[e];
  int p = rowp[d] + atomicAdd(&cur[d], 1);
  srcs[p] = src[e];
  ets[p] = etype[e];
  dsts[p] = d;
}

// ---------------- edge attention logits (sorted order, bf16 gather) ----------------
__global__ void k_att(const unsigned short* __restrict__ T1,
                      const unsigned short* __restrict__ T2,
                      const int* __restrict__ srcs, const int* __restrict__ dsts,
                      const int* __restrict__ ets, float* __restrict__ att) {
  int e = (blockIdx.x * 256 + threadIdx.x) >> 6;
  int lane = threadIdx.x & 63;
  if (e >= NE) return;
  int r = ets[e], s = srcs[e], d = dsts[e];
  float a = bf2f(T1[((long)r * NN + s) * 64 + lane]);
  float b = bf2f(T2[((long)r * NN + d) * 64 + lane]);
  float prod = a * b;
  prod += __shfl_xor(prod, 1);
  prod += __shfl_xor(prod, 2);
  prod += __shfl_xor(prod, 4);
  prod += __shfl_xor(prod, 8);
  float hv = __shfl(prod, (lane & 3) << 4);
  if (lane < 4) att[e * 4 + lane] = hv;
}

// ---------------- fused softmax + message + bi-transform, layer 0 ----------------
__global__ void k_fused0(const float* __restrict__ E, const unsigned short* __restrict__ Ebf,
                         const float* __restrict__ att, float* __restrict__ attn,
                         const int* __restrict__ rowp, const int* __restrict__ srcs,
                         const float* __restrict__ W1, const float* __restrict__ b1,
                         const float* __restrict__ W2, const float* __restrict__ b2,
                         float* __restrict__ ego1, unsigned short* __restrict__ ego1bf) {
  __shared__ float w1[512], w2[512], bb[16];
  __shared__ float s1[4][4][68], s2[4][4][68];
  int t = threadIdx.x;
  for (int i = t; i < 512; i += 256) { w1[i] = W1[i]; w2[i] = W2[i]; }
  if (t < 8) bb[t] = b1[t];
  else if (t < 16) bb[t] = b2[t - 8];
  __syncthreads();
  int wv = t >> 6, lane = t & 63;
  int n = blockIdx.x * 4 + wv;
  int p0 = rowp[n], p1 = rowp[n + 1];
  float ed = E[n * 64 + lane];
  // pass 1: per-head max (head class = lane&3)
  float m = -3.4e38f;
  for (int i = p0 * 4 + lane; i < p1 * 4; i += 64) m = fmaxf(m, att[i]);
  m = fmaxf(m, __shfl_xor(m, 4));
  m = fmaxf(m, __shfl_xor(m, 8));
  m = fmaxf(m, __shfl_xor(m, 16));
  m = fmaxf(m, __shfl_xor(m, 32));
  // pass 2: denom
  float z = 0.f;
  for (int i = p0 * 4 + lane; i < p1 * 4; i += 64) z += __expf(att[i] - m);
  z += __shfl_xor(z, 4);
  z += __shfl_xor(z, 8);
  z += __shfl_xor(z, 16);
  z += __shfl_xor(z, 32);
  float inv = 1.f / fmaxf(z, 1e-12f);
  // broadcast per-head m, inv (lanes 0..3 hold heads 0..3)
  float m0 = __shfl(m, 0), m1 = __shfl(m, 1), m2 = __shfl(m, 2), m3 = __shfl(m, 3);
  float i0 = __shfl(inv, 0), i1 = __shfl(inv, 1), i2 = __shfl(inv, 2), i3 = __shfl(inv, 3);
  // pass 3: accumulate messages with in-register normalization
  float a0 = 0.f, a1 = 0.f, a2 = 0.f, a3 = 0.f;
  for (int p = p0; p < p1; ++p) {
    int s = srcs[p];
    float4 a = ((const float4*)att)[p];
    float ax = __expf(a.x - m0) * i0;
    float ay = __expf(a.y - m1) * i1;
    float az = __expf(a.z - m2) * i2;
    float aw = __expf(a.w - m3) * i3;
    float ev = bf2f(Ebf[s * 64 + lane]);
    a0 += ev * ax; a1 += ev * ay; a2 += ev * az; a3 += ev * aw;
  }
  // pass 4: write normalized attention for layer-1 kernel
  for (int i = p0 * 4 + lane; i < p1 * 4; i += 64) attn[i] = __expf(att[i] - m) * inv;
  // transform
  s1[wv][0][lane] = ed + a0; s2[wv][0][lane] = ed * a0;
  s1[wv][1][lane] = ed + a1; s2[wv][1][lane] = ed * a1;
  s1[wv][2][lane] = ed + a2; s2[wv][2][lane] = ed * a2;
  s1[wv][3][lane] = ed + a3; s2[wv][3][lane] = ed * a3;
  __syncthreads();
  int h = (lane >> 3) & 3, j = lane & 7;
  const float* sp = (lane < 32) ? &s1[wv][h][0] : &s2[wv][h][0];
  const float* wp = (lane < 32) ? w1 : w2;
  float p = 0.f;
#pragma unroll
  for (int d = 0; d < 64; ++d) p += sp[d] * wp[d * 8 + j];
  p += (lane < 32) ? bb[j] : bb[8 + j];
  p = (p >= 0.f) ? p : 0.01f * p;
  float other = __shfl_xor(p, 32);
  if (lane < 32) {
    float o = p + other;
    ego1[n * 32 + h * 8 + j] = o;
    ego1bf[n * 32 + h * 8 + j] = f2bf(o);
  }
}

// ---------------- fused message + bi-transform, layer 1 ----------------
__global__ void k_fused1(const float* __restrict__ ego1, const unsigned short* __restrict__ E1bf,
                         const float* __restrict__ attn,
                         const int* __restrict__ rowp, const int* __restrict__ srcs,
                         const float* __restrict__ W1, const float* __restrict__ b1,
                         const float* __restrict__ W2, const float* __restrict__ b2,
                         float* __restrict__ ego2) {
  __shared__ float w1[128], w2[128], bb[8];
  __shared__ float s1[4][4][36], s2[4][4][36];
  int t = threadIdx.x;
  if (t < 128) w1[t] = W1[t];
  else if (t < 256) w2[t - 128] = W2[t - 128];
  if (t < 4) bb[t] = b1[t];
  else if (t < 8) bb[t] = b2[t - 4];
  __syncthreads();
  int wv = t >> 6, lane = t & 63;
  int n = blockIdx.x * 4 + wv;
  int d = lane & 31;
  bool up = lane >= 32;
  int p0 = rowp[n], p1 = rowp[n + 1];
  float aa = 0.f, ab = 0.f;
  for (int p = p0; p < p1; ++p) {
    int s = srcs[p];
    float4 a = ((const float4*)attn)[p];
    float ev = bf2f(E1bf[s * 32 + d]);
    float alo = up ? a.z : a.x;
    float ahi = up ? a.w : a.y;
    aa += ev * alo; ab += ev * ahi;
  }
  float e1 = ego1[n * 32 + d];
  int h0 = up ? 2 : 0, h1 = up ? 3 : 1;
  s1[wv][h0][d] = e1 + aa; s2[wv][h0][d] = e1 * aa;
  s1[wv][h1][d] = e1 + ab; s2[wv][h1][d] = e1 * ab;
  __syncthreads();
  if (lane < 32) {
    int h = (lane >> 2) & 3, j = lane & 3;
    const float* sp = (lane < 16) ? &s1[wv][h][0] : &s2[wv][h][0];
    const float* wp = (lane < 16) ? w1 : w2;
    float p = 0.f;
#pragma unroll
    for (int dd = 0; dd < 32; ++dd) p += sp[dd] * wp[dd * 4 + j];
    p += (lane < 16) ? bb[j] : bb[4 + j];
    p = (p >= 0.f) ? p : 0.01f * p;
    float other = __shfl_xor(p, 16);
    if (lane < 16) ego2[n * 16 + lane] = p + other;
  }
}

// ---------------- gather user/item rows with l2norm into U, V ----------------
__global__ void k_uv(const float* __restrict__ E, const float* __restrict__ E1,
                     const float* __restrict__ E2, const int* __restrict__ uid,
                     const int* __restrict__ iid, float* __restrict__ U,
                     float* __restrict__ V) {
  int row = (blockIdx.x * 256 + threadIdx.x) >> 6;
  int lane = threadIdx.x & 63;
  if (row >= 1000 + 4096) return;
  int id = (row < 1000) ? uid[row] : iid[row - 1000];
  float* dest = (row < 1000) ? (U + row * 112) : (V + (row - 1000) * 112);
  float v1 = (lane < 32) ? E1[id * 32 + lane] : 0.f;
  float s1 = v1 * v1;
  for (int m = 1; m < 64; m <<= 1) s1 += __shfl_xor(s1, m);
  float v2 = (lane < 16) ? E2[id * 16 + lane] : 0.f;
  float s2 = v2 * v2;
  for (int m = 1; m < 64; m <<= 1) s2 += __shfl_xor(s2, m);
  float i1 = 1.f / fmaxf(sqrtf(s1), 1e-12f);
  float i2 = 1.f / fmaxf(sqrtf(s2), 1e-12f);
  dest[lane] = E[id * 64 + lane];
  if (lane < 32) dest[64 + lane] = v1 * i1;
  if (lane < 16) dest[96 + lane] = v2 * i2;
}

// ---------------- final small GEMM: C[1000,4096] = U @ V^T (K=112) ----------------
__global__ void k_gemm(const float* __restrict__ U, const float* __restrict__ V,
                       float* __restrict__ C) {
  __shared__ float Us[16][113], Vs[16][113];
  int tx = threadIdx.x & 15, ty = threadIdx.x >> 4;
  int u0 = blockIdx.y * 16, v0 = blockIdx.x * 16;
  for (int i = threadIdx.x; i < 16 * 112; i += 256) {
    int rr = i / 112, cc = i % 112;
    int ur = u0 + rr;
    Us[rr][cc] = (ur < 1000) ? U[ur * 112 + cc] : 0.f;
    Vs[rr][cc] = V[(v0 + rr) * 112 + cc];
  }
  __syncthreads();
  int u = u0 + ty;
  if (u >= 1000) return;
  float acc = 0.f;
#pragma unroll
  for (int k = 0; k < 112; ++k) acc += Us[ty][k] * Vs[tx][k];
  C[u * 4096 + v0 + tx] = acc;
}

extern "C" void kernel_launch(void* const* d_in, const int* in_sizes, int n_in,
                              void* d_out, int out_size, void* d_ws, size_t ws_size,
                              hipStream_t stream) {
  const int* src = (const int*)d_in[0];
  const int* dst = (const int*)d_in[1];
  const int* etype = (const int*)d_in[2];
  const int* uid = (const int*)d_in[4];
  const int* iid = (const int*)d_in[5];
  const float* entity = (const float*)d_in[6];
  const float* rel = (const float*)d_in[7];
  const float* W_R = (const float*)d_in[8];
  const float* W_A = (const float*)d_in[9];
  const float* W1_0 = (const float*)d_in[10];
  const float* b1_0 = (const float*)d_in[11];
  const float* W2_0 = (const float*)d_in[12];
  const float* b2_0 = (const float*)d_in[13];
  const float* W1_1 = (const float*)d_in[14];
  const float* b1_1 = (const float*)d_in[15];
  const float* W2_1 = (const float*)d_in[16];
  const float* b2_1 = (const float*)d_in[17];
  float* out = (float*)d_out;

  char* ws = (char*)d_ws;
  // workspace layout (bytes); T1 region is reused after k_att for layer outputs,
  // T2 region is reused for normalized attention.
  unsigned short* T1   = (unsigned short*)(ws + 0);            // 102,400,000
  float*          ego1 = (float*)         (ws + 0);            //  12,800,000 (alias T1)
  unsigned short* e1bf = (unsigned short*)(ws + 12800000);     //   6,400,000 (alias T1)
  float*          ego2 = (float*)         (ws + 19200000);     //   6,400,000 (alias T1)
  float*          U    = (float*)         (ws + 25600000);     //     448,000 (alias T1)
  float*          V    = (float*)         (ws + 26048000);     //   1,835,008 (alias T1)
  unsigned short* T2   = (unsigned short*)(ws + 102400000);    // 102,400,000
  float*          attn = (float*)         (ws + 102400000);    //  25,600,000 (alias T2)
  float*          att  = (float*)         (ws + 204800000);    //  25,600,000
  int*            srcs = (int*)           (ws + 230400000);    //   6,400,000
  int*            ets  = (int*)           (ws + 236800000);    //   6,400,000
  int*            dsts = (int*)           (ws + 243200000);    //   6,400,000
  int*            rowp = (int*)           (ws + 249600000);    //     400,128
  int*            cnt  = (int*)           (ws + 250000128);    //     400,128
  int*            bsum = (int*)           (ws + 250400256);    //         512
  unsigned short* Wbf  = (unsigned short*)(ws + 250400768);    //      65,536
  float*          rea  = (float*)         (ws + 250531840);    //       2,048
  unsigned short* Ebf  = (unsigned short*)(ws + 250533888);    //  12,800,000
  // total: 263,333,888 bytes

  hipMemsetAsync(cnt, 0, NN * sizeof(int), stream);
  k_prep<<<130, 256, 0, stream>>>(W_R, W_A, rel, Wbf, rea);
  k_cvt<<<6250, 256, 0, stream>>>(entity, Ebf);
  k_proj<<<(NN + 63) / 64, 256, 0, stream>>>(Ebf, Wbf, rea, T1, T2);
  k_hist<<<NE / 256, 256, 0, stream>>>(dst, cnt);
  k_scan1<<<NSCAN, SCAN_B, 0, stream>>>(cnt, rowp, bsum);
  k_scan2<<<1, 64, 0, stream>>>(bsum);
  k_scan3<<<NSCAN, SCAN_B, 0, stream>>>(rowp, bsum);
  hipMemsetAsync(cnt, 0, NN * sizeof(int), stream);
  k_scatter<<<NE / 256, 256, 0, stream>>>(src, dst, etype, rowp, cnt, srcs, ets, dsts);
  k_att<<<NE / 4, 256, 0, stream>>>(T1, T2, srcs, dsts, ets, att);
  k_fused0<<<NN / 4, 256, 0, stream>>>(entity, Ebf, att, attn, rowp, srcs,
                                       W1_0, b1_0, W2_0, b2_0, ego1, e1bf);
  k_fused1<<<NN / 4, 256, 0, stream>>>(ego1, e1bf, attn, rowp, srcs,
                                       W1_1, b1_1, W2_1, b2_1, ego2);
  k_uv<<<(1000 + 4096 + 3) / 4, 256, 0, stream>>>(entity, ego1, ego2, uid, iid, U, V);
  k_gemm<<<dim3(4096 / 16, (1000 + 15) / 16), 256, 0, stream>>>(U, V, out);
}

// Round 4
// 741.064 us; speedup vs baseline: 1.8072x; 1.3809x over previous
//
#include <hip/hip_runtime.h>
#include <hip/hip_bf16.h>
#include <math.h>

#define NN 100000
#define NR 8
#define NE 1600000
// ED=RD=64, H=4, A=16, D1=32, D2=16

typedef __attribute__((ext_vector_type(8))) short short8v;
typedef __attribute__((ext_vector_type(4))) float float4v;
typedef __attribute__((ext_vector_type(2))) float float2v;

__device__ inline float bf2f(unsigned short u) {
  union { unsigned int i; float f; } v; v.i = ((unsigned int)u) << 16; return v.f;
}
__device__ inline unsigned short f2bf(float f) {
  __hip_bfloat16 h = __float2bfloat16(f);
  return *reinterpret_cast<unsigned short*>(&h);
}
__device__ inline float fast_tanh(float x) {
  float ex = __expf(2.f * x);
  return 1.f - 2.f * __builtin_amdgcn_rcpf(ex + 1.f);
}
__device__ inline unsigned char f2fp8(float f) {
  unsigned int p = __builtin_amdgcn_cvt_pk_fp8_f32(f, f, 0, false);
  return (unsigned char)(p & 0xff);
}

// ---------------- weight prep: Wbf[c][e] bf16 col-major, rea[512] ----------------
__global__ void k_prep(const float* __restrict__ W_R, const float* __restrict__ W_A,
                       const float* __restrict__ rel, unsigned short* __restrict__ Wbf,
                       float* __restrict__ r_emb_a) {
  int tid = blockIdx.x * 256 + threadIdx.x;
  if (tid < NR * 64 * 64) {
    int r = tid >> 12;
    int i = (tid >> 6) & 63;   // embed dim e
    int k = tid & 63;          // output dim within relation
    float acc = 0.f;
    const float* wr = W_R + (r * 64 + i) * 64;
    for (int j = 0; j < 64; ++j) acc += wr[j] * W_A[j * 64 + k];
    Wbf[(r * 64 + k) * 64 + i] = f2bf(acc);   // col-major: [c=r*64+k][e=i]
  } else if (tid < NR * 64 * 64 + NR * 64) {
    int idx = tid - NR * 64 * 64;
    int r = idx >> 6, k = idx & 63;
    float acc = 0.f;
    for (int j = 0; j < 64; ++j) acc += rel[r * 64 + j] * W_A[j * 64 + k];
    r_emb_a[idx] = acc;
  }
}

// ---------------- entity -> bf16 copy ----------------
__global__ void k_cvt(const float* __restrict__ E, unsigned short* __restrict__ Ebf) {
  int i = blockIdx.x * 256 + threadIdx.x;  // handles 4 floats
  float4 v = ((const float4*)E)[i];
  ushort4 o;
  o.x = f2bf(v.x); o.y = f2bf(v.y); o.z = f2bf(v.z); o.w = f2bf(v.w);
  ((ushort4*)Ebf)[i] = o;
}

// ---------------- proj via MFMA: T1/T2[r][n][k] = tanh(E@W_ra (+rea)) fp8 ----------------
// Block = 64 nodes (4 waves x 16). Wave computes its 16 nodes x all 512 cols.
__global__ void k_proj(const unsigned short* __restrict__ Ebf,
                       const unsigned short* __restrict__ Wbf,
                       const float* __restrict__ rea,
                       unsigned char* __restrict__ T1, unsigned char* __restrict__ T2) {
  int wv = threadIdx.x >> 6, lane = threadIdx.x & 63;
  int n0 = blockIdx.x * 64 + wv * 16;
  int mrow = lane & 15, kg = lane >> 4;  // kg in 0..3
  int nodeA = n0 + mrow;
  if (nodeA >= NN) nodeA = NN - 1;
  const short8v a0 = *(const short8v*)(Ebf + (long)nodeA * 64 + kg * 8);
  const short8v a1 = *(const short8v*)(Ebf + (long)nodeA * 64 + 32 + kg * 8);
  int orow = kg * 4;  // output row group for this lane
  for (int ct = 0; ct < 32; ++ct) {
    int c = ct * 16 + mrow;  // global output column 0..511
    const short8v b0 = *(const short8v*)(Wbf + c * 64 + kg * 8);
    const short8v b1 = *(const short8v*)(Wbf + c * 64 + 32 + kg * 8);
    float4v acc = {0.f, 0.f, 0.f, 0.f};
    acc = __builtin_amdgcn_mfma_f32_16x16x32_bf16(a0, b0, acc, 0, 0, 0);
    acc = __builtin_amdgcn_mfma_f32_16x16x32_bf16(a1, b1, acc, 0, 0, 0);
    float rv = rea[c];
    int r = c >> 6, kk = c & 63;
#pragma unroll
    for (int i = 0; i < 4; ++i) {
      int nd = n0 + orow + i;
      if (nd < NN) {
        long base = ((long)r * NN + nd) * 64 + kk;
        T1[base] = f2fp8(fast_tanh(acc[i]));
        T2[base] = f2fp8(fast_tanh(acc[i] + rv));
      }
    }
  }
}

// ---------------- CSR build ----------------
__global__ void k_hist(const int* __restrict__ dst, int* __restrict__ cnt) {
  int e = blockIdx.x * 256 + threadIdx.x;
  if (e < NE) atomicAdd(&cnt[dst[e]], 1);
}

#define SCAN_B 1024
#define NSCAN ((NN + SCAN_B - 1) / SCAN_B)  // 98

__global__ void k_scan1(const int* __restrict__ cnt, int* __restrict__ rowp,
                        int* __restrict__ bsum) {
  __shared__ int s[SCAN_B];
  int t = threadIdx.x, g = blockIdx.x * SCAN_B + t;
  s[t] = (g < NN) ? cnt[g] : 0;
  __syncthreads();
  for (int off = 1; off < SCAN_B; off <<= 1) {
    int x = (t >= off) ? s[t - off] : 0;
    __syncthreads();
    s[t] += x;
    __syncthreads();
  }
  if (g < NN) rowp[g + 1] = s[t];
  if (t == SCAN_B - 1) bsum[blockIdx.x] = s[t];
}

__global__ void k_scan2(int* bsum) {
  if (threadIdx.x == 0) {
    int acc = 0;
    for (int i = 0; i < NSCAN; ++i) { int v = bsum[i]; bsum[i] = acc; acc += v; }
  }
}

__global__ void k_scan3(int* rowp, const int* __restrict__ bsum) {
  int t = threadIdx.x, g = blockIdx.x * SCAN_B + t;
  if (g < NN) rowp[g + 1] += bsum[blockIdx.x];
  if (g == 0) rowp[0] = 0;
}

__global__ void k_scatter(const int* __restrict__ src, const int* __restrict__ dst,
                          const int* __restrict__ etype, const int* __restrict__ rowp,
                          int* __restrict__ cur, int* __restrict__ srcs,
                          int* __restrict__ ets, int* __restrict__ dsts) {
  int e = blockIdx.x * 256 + threadIdx.x;
  if (e >= NE) return;
  int d = dst[e];
  int p = rowp[d] + atomicAdd(&cur[d], 1);
  srcs[p] = src[e];
  ets[p] = etype[e];
  dsts[p] = d;
}

// ---------------- edge attention logits: 4 lanes/edge, fp8 dot ----------------
__global__ void k_att(const unsigned char* __restrict__ T1,
                      const unsigned char* __restrict__ T2,
                      const int* __restrict__ srcs, const int* __restrict__ dsts,
                      const int* __restrict__ ets, float* __restrict__ att) {
  int gid = blockIdx.x * 256 + threadIdx.x;
  int e = gid >> 2;  // 4 lanes per edge, lane = head
  int h = gid & 3;
  if (e >= NE) return;
  int r = ets[e], s = srcs[e], d = dsts[e];
  const uint4 av = *(const uint4*)(T1 + ((long)r * NN + s) * 64 + h * 16);
  const uint4 bv = *(const uint4*)(T2 + ((long)r * NN + d) * 64 + h * 16);
  const unsigned int* ap = (const unsigned int*)&av;
  const unsigned int* bp = (const unsigned int*)&bv;
  float acc = 0.f;
#pragma unroll
  for (int i = 0; i < 4; ++i) {
    float2v a0 = __builtin_amdgcn_cvt_pk_f32_fp8(ap[i], false);
    float2v a1 = __builtin_amdgcn_cvt_pk_f32_fp8(ap[i], true);
    float2v b0 = __builtin_amdgcn_cvt_pk_f32_fp8(bp[i], false);
    float2v b1 = __builtin_amdgcn_cvt_pk_f32_fp8(bp[i], true);
    acc += a0.x * b0.x + a0.y * b0.y + a1.x * b1.x + a1.y * b1.y;
  }
  att[e * 4 + h] = acc;
}

// ---------------- fused softmax + message + bi-transform, layer 0 ----------------
__global__ void k_fused0(const float* __restrict__ E, const unsigned short* __restrict__ Ebf,
                         const float* __restrict__ att, float* __restrict__ attn,
                         const int* __restrict__ rowp, const int* __restrict__ srcs,
                         const float* __restrict__ W1, const float* __restrict__ b1,
                         const float* __restrict__ W2, const float* __restrict__ b2,
                         float* __restrict__ ego1, unsigned short* __restrict__ ego1bf) {
  __shared__ float w1[512], w2[512], bb[16];
  __shared__ float s1[4][4][68], s2[4][4][68];
  int t = threadIdx.x;
  for (int i = t; i < 512; i += 256) { w1[i] = W1[i]; w2[i] = W2[i]; }
  if (t < 8) bb[t] = b1[t];
  else if (t < 16) bb[t] = b2[t - 8];
  __syncthreads();
  int wv = t >> 6, lane = t & 63;
  int n = blockIdx.x * 4 + wv;
  int p0 = rowp[n], p1 = rowp[n + 1];
  float ed = E[n * 64 + lane];
  // pass 1: per-head max (head class = lane&3)
  float m = -3.4e38f;
  for (int i = p0 * 4 + lane; i < p1 * 4; i += 64) m = fmaxf(m, att[i]);
  m = fmaxf(m, __shfl_xor(m, 4));
  m = fmaxf(m, __shfl_xor(m, 8));
  m = fmaxf(m, __shfl_xor(m, 16));
  m = fmaxf(m, __shfl_xor(m, 32));
  // pass 2: denom
  float z = 0.f;
  for (int i = p0 * 4 + lane; i < p1 * 4; i += 64) z += __expf(att[i] - m);
  z += __shfl_xor(z, 4);
  z += __shfl_xor(z, 8);
  z += __shfl_xor(z, 16);
  z += __shfl_xor(z, 32);
  float inv = 1.f / fmaxf(z, 1e-12f);
  // broadcast per-head m, inv (lanes 0..3 hold heads 0..3)
  float m0 = __shfl(m, 0), m1 = __shfl(m, 1), m2 = __shfl(m, 2), m3 = __shfl(m, 3);
  float i0 = __shfl(inv, 0), i1 = __shfl(inv, 1), i2 = __shfl(inv, 2), i3 = __shfl(inv, 3);
  // pass 3: accumulate messages with in-register normalization
  float a0 = 0.f, a1 = 0.f, a2 = 0.f, a3 = 0.f;
  for (int p = p0; p < p1; ++p) {
    int s = srcs[p];
    float4 a = ((const float4*)att)[p];
    float ax = __expf(a.x - m0) * i0;
    float ay = __expf(a.y - m1) * i1;
    float az = __expf(a.z - m2) * i2;
    float aw = __expf(a.w - m3) * i3;
    float ev = bf2f(Ebf[s * 64 + lane]);
    a0 += ev * ax; a1 += ev * ay; a2 += ev * az; a3 += ev * aw;
  }
  // pass 4: write normalized attention for layer-1 kernel
  for (int i = p0 * 4 + lane; i < p1 * 4; i += 64) attn[i] = __expf(att[i] - m) * inv;
  // transform
  s1[wv][0][lane] = ed + a0; s2[wv][0][lane] = ed * a0;
  s1[wv][1][lane] = ed + a1; s2[wv][1][lane] = ed * a1;
  s1[wv][2][lane] = ed + a2; s2[wv][2][lane] = ed * a2;
  s1[wv][3][lane] = ed + a3; s2[wv][3][lane] = ed * a3;
  __syncthreads();
  int h = (lane >> 3) & 3, j = lane & 7;
  const float* sp = (lane < 32) ? &s1[wv][h][0] : &s2[wv][h][0];
  const float* wp = (lane < 32) ? w1 : w2;
  float p = 0.f;
#pragma unroll
  for (int d = 0; d < 64; ++d) p += sp[d] * wp[d * 8 + j];
  p += (lane < 32) ? bb[j] : bb[8 + j];
  p = (p >= 0.f) ? p : 0.01f * p;
  float other = __shfl_xor(p, 32);
  if (lane < 32) {
    float o = p + other;
    ego1[n * 32 + h * 8 + j] = o;
    ego1bf[n * 32 + h * 8 + j] = f2bf(o);
  }
}

// ---------------- fused message + bi-transform, layer 1 ----------------
__global__ void k_fused1(const float* __restrict__ ego1, const unsigned short* __restrict__ E1bf,
                         const float* __restrict__ attn,
                         const int* __restrict__ rowp, const int* __restrict__ srcs,
                         const float* __restrict__ W1, const float* __restrict__ b1,
                         const float* __restrict__ W2, const float* __restrict__ b2,
                         float* __restrict__ ego2) {
  __shared__ float w1[128], w2[128], bb[8];
  __shared__ float s1[4][4][36], s2[4][4][36];
  int t = threadIdx.x;
  if (t < 128) w1[t] = W1[t];
  else if (t < 256) w2[t - 128] = W2[t - 128];
  if (t < 4) bb[t] = b1[t];
  else if (t < 8) bb[t] = b2[t - 4];
  __syncthreads();
  int wv = t >> 6, lane = t & 63;
  int n = blockIdx.x * 4 + wv;
  int d = lane & 31;
  bool up = lane >= 32;
  int p0 = rowp[n], p1 = rowp[n + 1];
  float aa = 0.f, ab = 0.f;
  for (int p = p0; p < p1; ++p) {
    int s = srcs[p];
    float4 a = ((const float4*)attn)[p];
    float ev = bf2f(E1bf[s * 32 + d]);
    float alo = up ? a.z : a.x;
    float ahi = up ? a.w : a.y;
    aa += ev * alo; ab += ev * ahi;
  }
  float e1 = ego1[n * 32 + d];
  int h0 = up ? 2 : 0, h1 = up ? 3 : 1;
  s1[wv][h0][d] = e1 + aa; s2[wv][h0][d] = e1 * aa;
  s1[wv][h1][d] = e1 + ab; s2[wv][h1][d] = e1 * ab;
  __syncthreads();
  if (lane < 32) {
    int h = (lane >> 2) & 3, j = lane & 3;
    const float* sp = (lane < 16) ? &s1[wv][h][0] : &s2[wv][h][0];
    const float* wp = (lane < 16) ? w1 : w2;
    float p = 0.f;
#pragma unroll
    for (int dd = 0; dd < 32; ++dd) p += sp[dd] * wp[dd * 4 + j];
    p += (lane < 16) ? bb[j] : bb[4 + j];
    p = (p >= 0.f) ? p : 0.01f * p;
    float other = __shfl_xor(p, 16);
    if (lane < 16) ego2[n * 16 + lane] = p + other;
  }
}

// ---------------- gather user/item rows with l2norm into U, V ----------------
__global__ void k_uv(const float* __restrict__ E, const float* __restrict__ E1,
                     const float* __restrict__ E2, const int* __restrict__ uid,
                     const int* __restrict__ iid, float* __restrict__ U,
                     float* __restrict__ V) {
  int row = (blockIdx.x * 256 + threadIdx.x) >> 6;
  int lane = threadIdx.x & 63;
  if (row >= 1000 + 4096) return;
  int id = (row < 1000) ? uid[row] : iid[row - 1000];
  float* dest = (row < 1000) ? (U + row * 112) : (V + (row - 1000) * 112);
  float v1 = (lane < 32) ? E1[id * 32 + lane] : 0.f;
  float s1 = v1 * v1;
  for (int m = 1; m < 64; m <<= 1) s1 += __shfl_xor(s1, m);
  float v2 = (lane < 16) ? E2[id * 16 + lane] : 0.f;
  float s2 = v2 * v2;
  for (int m = 1; m < 64; m <<= 1) s2 += __shfl_xor(s2, m);
  float i1 = 1.f / fmaxf(sqrtf(s1), 1e-12f);
  float i2 = 1.f / fmaxf(sqrtf(s2), 1e-12f);
  dest[lane] = E[id * 64 + lane];
  if (lane < 32) dest[64 + lane] = v1 * i1;
  if (lane < 16) dest[96 + lane] = v2 * i2;
}

// ---------------- final small GEMM: C[1000,4096] = U @ V^T (K=112) ----------------
__global__ void k_gemm(const float* __restrict__ U, const float* __restrict__ V,
                       float* __restrict__ C) {
  __shared__ float Us[16][113], Vs[16][113];
  int tx = threadIdx.x & 15, ty = threadIdx.x >> 4;
  int u0 = blockIdx.y * 16, v0 = blockIdx.x * 16;
  for (int i = threadIdx.x; i < 16 * 112; i += 256) {
    int rr = i / 112, cc = i % 112;
    int ur = u0 + rr;
    Us[rr][cc] = (ur < 1000) ? U[ur * 112 + cc] : 0.f;
    Vs[rr][cc] = V[(v0 + rr) * 112 + cc];
  }
  __syncthreads();
  int u = u0 + ty;
  if (u >= 1000) return;
  float acc = 0.f;
#pragma unroll
  for (int k = 0; k < 112; ++k) acc += Us[ty][k] * Vs[tx][k];
  C[u * 4096 + v0 + tx] = acc;
}

extern "C" void kernel_launch(void* const* d_in, const int* in_sizes, int n_in,
                              void* d_out, int out_size, void* d_ws, size_t ws_size,
                              hipStream_t stream) {
  const int* src = (const int*)d_in[0];
  const int* dst = (const int*)d_in[1];
  const int* etype = (const int*)d_in[2];
  const int* uid = (const int*)d_in[4];
  const int* iid = (const int*)d_in[5];
  const float* entity = (const float*)d_in[6];
  const float* rel = (const float*)d_in[7];
  const float* W_R = (const float*)d_in[8];
  const float* W_A = (const float*)d_in[9];
  const float* W1_0 = (const float*)d_in[10];
  const float* b1_0 = (const float*)d_in[11];
  const float* W2_0 = (const float*)d_in[12];
  const float* b2_0 = (const float*)d_in[13];
  const float* W1_1 = (const float*)d_in[14];
  const float* b1_1 = (const float*)d_in[15];
  const float* W2_1 = (const float*)d_in[16];
  const float* b2_1 = (const float*)d_in[17];
  float* out = (float*)d_out;

  char* ws = (char*)d_ws;
  // workspace layout (bytes); T1 region reused after k_att for layer outputs,
  // T2 region reused for normalized attention.
  unsigned char*  T1   = (unsigned char*) (ws + 0);            //  51,200,000
  float*          ego1 = (float*)         (ws + 0);            //  12,800,000 (alias T1)
  unsigned short* e1bf = (unsigned short*)(ws + 12800000);     //   6,400,000 (alias T1)
  float*          ego2 = (float*)         (ws + 19200000);     //   6,400,000 (alias T1)
  float*          U    = (float*)         (ws + 25600000);     //     448,000 (alias T1)
  float*          V    = (float*)         (ws + 26048000);     //   1,835,008 (alias T1)
  unsigned char*  T2   = (unsigned char*) (ws + 51200000);     //  51,200,000
  float*          attn = (float*)         (ws + 51200000);     //  25,600,000 (alias T2)
  float*          att  = (float*)         (ws + 102400000);    //  25,600,000
  int*            srcs = (int*)           (ws + 128000000);    //   6,400,000
  int*            ets  = (int*)           (ws + 134400000);    //   6,400,000
  int*            dsts = (int*)           (ws + 140800000);    //   6,400,000
  int*            rowp = (int*)           (ws + 147200000);    //     400,128
  int*            cnt  = (int*)           (ws + 147600128);    //     400,128
  int*            bsum = (int*)           (ws + 148000256);    //         512
  unsigned short* Wbf  = (unsigned short*)(ws + 148000768);    //      65,536
  float*          rea  = (float*)         (ws + 148066304);    //       2,048
  unsigned short* Ebf  = (unsigned short*)(ws + 148068352);    //  12,800,000
  // total: 160,868,352 bytes

  hipMemsetAsync(cnt, 0, NN * sizeof(int), stream);
  k_prep<<<130, 256, 0, stream>>>(W_R, W_A, rel, Wbf, rea);
  k_cvt<<<6250, 256, 0, stream>>>(entity, Ebf);
  k_proj<<<(NN + 63) / 64, 256, 0, stream>>>(Ebf, Wbf, rea, T1, T2);
  k_hist<<<NE / 256, 256, 0, stream>>>(dst, cnt);
  k_scan1<<<NSCAN, SCAN_B, 0, stream>>>(cnt, rowp, bsum);
  k_scan2<<<1, 64, 0, stream>>>(bsum);
  k_scan3<<<NSCAN, SCAN_B, 0, stream>>>(rowp, bsum);
  hipMemsetAsync(cnt, 0, NN * sizeof(int), stream);
  k_scatter<<<NE / 256, 256, 0, stream>>>(src, dst, etype, rowp, cnt, srcs, ets, dsts);
  k_att<<<NE * 4 / 256, 256, 0, stream>>>(T1, T2, srcs, dsts, ets, att);
  k_fused0<<<NN / 4, 256, 0, stream>>>(entity, Ebf, att, attn, rowp, srcs,
                                       W1_0, b1_0, W2_0, b2_0, ego1, e1bf);
  k_fused1<<<NN / 4, 256, 0, stream>>>(ego1, e1bf, attn, rowp, srcs,
                                       W1_1, b1_1, W2_1, b2_1, ego2);
  k_uv<<<(1000 + 4096 + 3) / 4, 256, 0, stream>>>(entity, ego1, ego2, uid, iid, U, V);
  k_gemm<<<dim3(4096 / 16, (1000 + 15) / 16), 256, 0, stream>>>(U, V, out);
}

// Round 6
// 593.045 us; speedup vs baseline: 2.2583x; 1.2496x over previous
//
#include <hip/hip_runtime.h>
#include <hip/hip_bf16.h>
#include <math.h>

#define NN 100000
#define NR 8
#define NE 1600000
// ED=RD=64, H=4, A=16, D1=32, D2=16

typedef __attribute__((ext_vector_type(8))) short short8v;
typedef __attribute__((ext_vector_type(4))) float float4v;
typedef __attribute__((ext_vector_type(2))) float float2v;

__device__ inline float bf2f(unsigned short u) {
  union { unsigned int i; float f; } v; v.i = ((unsigned int)u) << 16; return v.f;
}
__device__ inline unsigned short f2bf(float f) {
  __hip_bfloat16 h = __float2bfloat16(f);
  return *reinterpret_cast<unsigned short*>(&h);
}
__device__ inline float fast_tanh(float x) {
  float ex = __expf(2.f * x);
  return 1.f - 2.f * __builtin_amdgcn_rcpf(ex + 1.f);
}
__device__ inline unsigned char f2fp8(float f) {
  unsigned int p = __builtin_amdgcn_cvt_pk_fp8_f32(f, f, 0, false);
  return (unsigned char)(p & 0xff);
}

// ---------------- weight prep: Wbf[c][e] bf16 col-major, rea[512] ----------------
__global__ void k_prep(const float* __restrict__ W_R, const float* __restrict__ W_A,
                       const float* __restrict__ rel, unsigned short* __restrict__ Wbf,
                       float* __restrict__ r_emb_a) {
  int tid = blockIdx.x * 256 + threadIdx.x;
  if (tid < NR * 64 * 64) {
    int r = tid >> 12;
    int i = (tid >> 6) & 63;   // embed dim e
    int k = tid & 63;          // output dim within relation
    float acc = 0.f;
    const float* wr = W_R + (r * 64 + i) * 64;
    for (int j = 0; j < 64; ++j) acc += wr[j] * W_A[j * 64 + k];
    Wbf[(r * 64 + k) * 64 + i] = f2bf(acc);   // col-major: [c=r*64+k][e=i]
  } else if (tid < NR * 64 * 64 + NR * 64) {
    int idx = tid - NR * 64 * 64;
    int r = idx >> 6, k = idx & 63;
    float acc = 0.f;
    for (int j = 0; j < 64; ++j) acc += rel[r * 64 + j] * W_A[j * 64 + k];
    r_emb_a[idx] = acc;
  }
}

// ---------------- entity -> bf16 copy ----------------
__global__ void k_cvt(const float* __restrict__ E, unsigned short* __restrict__ Ebf) {
  int i = blockIdx.x * 256 + threadIdx.x;  // handles 4 floats
  float4 v = ((const float4*)E)[i];
  ushort4 o;
  o.x = f2bf(v.x); o.y = f2bf(v.y); o.z = f2bf(v.z); o.w = f2bf(v.w);
  ((ushort4*)Ebf)[i] = o;
}

// ---------------- proj via MFMA: T1/T2[r][n][k] = tanh(E@W_ra (+rea)) fp8 ----------------
__global__ void k_proj(const unsigned short* __restrict__ Ebf,
                       const unsigned short* __restrict__ Wbf,
                       const float* __restrict__ rea,
                       unsigned char* __restrict__ T1, unsigned char* __restrict__ T2) {
  int wv = threadIdx.x >> 6, lane = threadIdx.x & 63;
  int n0 = blockIdx.x * 64 + wv * 16;
  int mrow = lane & 15, kg = lane >> 4;  // kg in 0..3
  int nodeA = n0 + mrow;
  if (nodeA >= NN) nodeA = NN - 1;
  const short8v a0 = *(const short8v*)(Ebf + (long)nodeA * 64 + kg * 8);
  const short8v a1 = *(const short8v*)(Ebf + (long)nodeA * 64 + 32 + kg * 8);
  int orow = kg * 4;  // output row group for this lane
  for (int ct = 0; ct < 32; ++ct) {
    int c = ct * 16 + mrow;  // global output column 0..511
    const short8v b0 = *(const short8v*)(Wbf + c * 64 + kg * 8);
    const short8v b1 = *(const short8v*)(Wbf + c * 64 + 32 + kg * 8);
    float4v acc = {0.f, 0.f, 0.f, 0.f};
    acc = __builtin_amdgcn_mfma_f32_16x16x32_bf16(a0, b0, acc, 0, 0, 0);
    acc = __builtin_amdgcn_mfma_f32_16x16x32_bf16(a1, b1, acc, 0, 0, 0);
    float rv = rea[c];
    int r = c >> 6, kk = c & 63;
#pragma unroll
    for (int i = 0; i < 4; ++i) {
      int nd = n0 + orow + i;
      if (nd < NN) {
        long base = ((long)r * NN + nd) * 64 + kk;
        T1[base] = f2fp8(fast_tanh(acc[i]));
        T2[base] = f2fp8(fast_tanh(acc[i] + rv));
      }
    }
  }
}

// ---------------- CSR build ----------------
__global__ void k_hist(const int* __restrict__ dst, int* __restrict__ cnt) {
  int e = blockIdx.x * 256 + threadIdx.x;
  if (e < NE) atomicAdd(&cnt[dst[e]], 1);
}

#define SCAN_B 1024
#define NSCAN ((NN + SCAN_B - 1) / SCAN_B)  // 98

__global__ void k_scan1(const int* __restrict__ cnt, int* __restrict__ rowp,
                        int* __restrict__ bsum) {
  __shared__ int s[SCAN_B];
  int t = threadIdx.x, g = blockIdx.x * SCAN_B + t;
  s[t] = (g < NN) ? cnt[g] : 0;
  __syncthreads();
  for (int off = 1; off < SCAN_B; off <<= 1) {
    int x = (t >= off) ? s[t - off] : 0;
    __syncthreads();
    s[t] += x;
    __syncthreads();
  }
  if (g < NN) rowp[g + 1] = s[t];
  if (t == SCAN_B - 1) bsum[blockIdx.x] = s[t];
}

__global__ void k_scan2(int* bsum) {
  if (threadIdx.x == 0) {
    int acc = 0;
    for (int i = 0; i < NSCAN; ++i) { int v = bsum[i]; bsum[i] = acc; acc += v; }
  }
}

__global__ void k_scan3(int* rowp, const int* __restrict__ bsum) {
  int t = threadIdx.x, g = blockIdx.x * SCAN_B + t;
  if (g < NN) rowp[g + 1] += bsum[blockIdx.x];
  if (g == 0) rowp[0] = 0;
}

__global__ void k_scatter(const int* __restrict__ src, const int* __restrict__ dst,
                          const int* __restrict__ etype, const int* __restrict__ rowp,
                          int* __restrict__ cur, int* __restrict__ srcs,
                          int* __restrict__ ets, int* __restrict__ dsts) {
  int e = blockIdx.x * 256 + threadIdx.x;
  if (e >= NE) return;
  int d = dst[e];
  int p = rowp[d] + atomicAdd(&cur[d], 1);
  srcs[p] = src[e];
  ets[p] = etype[e];
  dsts[p] = d;
}

// ---------------- edge attention logits: 4 lanes/edge, fp8 dot ----------------
__global__ void k_att(const unsigned char* __restrict__ T1,
                      const unsigned char* __restrict__ T2,
                      const int* __restrict__ srcs, const int* __restrict__ dsts,
                      const int* __restrict__ ets, float* __restrict__ att) {
  int gid = blockIdx.x * 256 + threadIdx.x;
  int e = gid >> 2;  // 4 lanes per edge, lane = head
  int h = gid & 3;
  if (e >= NE) return;
  int r = ets[e], s = srcs[e], d = dsts[e];
  const uint4 av = *(const uint4*)(T1 + ((long)r * NN + s) * 64 + h * 16);
  const uint4 bv = *(const uint4*)(T2 + ((long)r * NN + d) * 64 + h * 16);
  const unsigned int* ap = (const unsigned int*)&av;
  const unsigned int* bp = (const unsigned int*)&bv;
  float acc = 0.f;
#pragma unroll
  for (int i = 0; i < 4; ++i) {
    float2v a0 = __builtin_amdgcn_cvt_pk_f32_fp8(ap[i], false);
    float2v a1 = __builtin_amdgcn_cvt_pk_f32_fp8(ap[i], true);
    float2v b0 = __builtin_amdgcn_cvt_pk_f32_fp8(bp[i], false);
    float2v b1 = __builtin_amdgcn_cvt_pk_f32_fp8(bp[i], true);
    acc += a0.x * b0.x + a0.y * b0.y + a1.x * b1.x + a1.y * b1.y;
  }
  att[e * 4 + h] = acc;
}

// ---------------- per-(node,head) softmax stats: m and 1/z ----------------
__global__ void k_nodemax(const int* __restrict__ rowp, const float* __restrict__ att,
                          float* __restrict__ minv) {
  int gid = blockIdx.x * 256 + threadIdx.x;
  int n = gid >> 2, h = gid & 3;
  if (n >= NN) return;
  int p0 = rowp[n], p1 = rowp[n + 1];
  float m = -3.4e38f;
  for (int p = p0; p < p1; ++p) m = fmaxf(m, att[p * 4 + h]);
  float z = 0.f;
  for (int p = p0; p < p1; ++p) z += __expf(att[p * 4 + h] - m);
  minv[n * 8 + h] = m;
  minv[n * 8 + 4 + h] = 1.f / fmaxf(z, 1e-12f);
}

// ---------------- edge-parallel normalized attention ----------------
__global__ void k_attn(const float* __restrict__ att, const float* __restrict__ minv,
                       const int* __restrict__ dsts, float* __restrict__ attn) {
  int gid = blockIdx.x * 256 + threadIdx.x;
  int e = gid >> 2, h = gid & 3;
  if (e >= NE) return;
  int d = dsts[e];
  attn[gid] = __expf(att[gid] - minv[d * 8 + h]) * minv[d * 8 + 4 + h];
}

// ---------------- fused message + bi-transform, layer 0 ----------------
// wave per node; 4 edges/iter; lane = (edge-slot g=lane>>4, dim-block q=lane&15)
__global__ void k_fused0(const float* __restrict__ E, const unsigned short* __restrict__ Ebf,
                         const float* __restrict__ attn,
                         const int* __restrict__ rowp, const int* __restrict__ srcs,
                         const float* __restrict__ W1, const float* __restrict__ b1,
                         const float* __restrict__ W2, const float* __restrict__ b2,
                         float* __restrict__ ego1, unsigned short* __restrict__ ego1bf) {
  __shared__ float wt1[8][68], wt2[8][68];  // transposed weights [j][d]
  __shared__ float bb[16];
  __shared__ float s1[4][4][68], s2[4][4][68];
  int t = threadIdx.x;
  for (int i = t; i < 512; i += 256) {
    int d = i >> 3, j = i & 7;
    wt1[j][d] = W1[i];
    wt2[j][d] = W2[i];
  }
  if (t < 8) bb[t] = b1[t];
  else if (t < 16) bb[t] = b2[t - 8];
  __syncthreads();
  int wv = t >> 6, lane = t & 63;
  int n = blockIdx.x * 4 + wv;
  int p0 = rowp[n], p1 = rowp[n + 1];
  int g = lane >> 4, q = lane & 15;
  float acc[4][4];  // [head][dim within block]
#pragma unroll
  for (int h = 0; h < 4; ++h)
#pragma unroll
    for (int j = 0; j < 4; ++j) acc[h][j] = 0.f;
  for (int p = p0 + g; p < p1; p += 4) {
    int s = srcs[p];
    float4 a = ((const float4*)attn)[p];
    ushort4 ev = *(const ushort4*)(Ebf + s * 64 + q * 4);
    float e0 = bf2f(ev.x), e1 = bf2f(ev.y), e2 = bf2f(ev.z), e3 = bf2f(ev.w);
    acc[0][0] += a.x * e0; acc[0][1] += a.x * e1; acc[0][2] += a.x * e2; acc[0][3] += a.x * e3;
    acc[1][0] += a.y * e0; acc[1][1] += a.y * e1; acc[1][2] += a.y * e2; acc[1][3] += a.y * e3;
    acc[2][0] += a.z * e0; acc[2][1] += a.z * e1; acc[2][2] += a.z * e2; acc[2][3] += a.z * e3;
    acc[3][0] += a.w * e0; acc[3][1] += a.w * e1; acc[3][2] += a.w * e2; acc[3][3] += a.w * e3;
  }
#pragma unroll
  for (int h = 0; h < 4; ++h)
#pragma unroll
    for (int j = 0; j < 4; ++j) {
      acc[h][j] += __shfl_xor(acc[h][j], 16);
      acc[h][j] += __shfl_xor(acc[h][j], 32);
    }
  if (lane < 16) {
    float4 edv = *(const float4*)(E + n * 64 + q * 4);
#pragma unroll
    for (int h = 0; h < 4; ++h) {
      float4 v1, v2;
      v1.x = edv.x + acc[h][0]; v2.x = edv.x * acc[h][0];
      v1.y = edv.y + acc[h][1]; v2.y = edv.y * acc[h][1];
      v1.z = edv.z + acc[h][2]; v2.z = edv.z * acc[h][2];
      v1.w = edv.w + acc[h][3]; v2.w = edv.w * acc[h][3];
      *(float4*)&s1[wv][h][q * 4] = v1;
      *(float4*)&s2[wv][h][q * 4] = v2;
    }
  }
  __syncthreads();
  int h = (lane >> 3) & 3, j = lane & 7;
  const float* sp = (lane < 32) ? &s1[wv][h][0] : &s2[wv][h][0];
  const float* wp = (lane < 32) ? &wt1[j][0] : &wt2[j][0];
  float o = 0.f;
#pragma unroll
  for (int d = 0; d < 64; d += 4) {
    float4 sv = *(const float4*)(sp + d);
    float4 wv4 = *(const float4*)(wp + d);
    o += sv.x * wv4.x + sv.y * wv4.y + sv.z * wv4.z + sv.w * wv4.w;
  }
  o += (lane < 32) ? bb[j] : bb[8 + j];
  o = (o >= 0.f) ? o : 0.01f * o;
  float other = __shfl_xor(o, 32);
  if (lane < 32) {
    float r = o + other;
    ego1[n * 32 + h * 8 + j] = r;
    ego1bf[n * 32 + h * 8 + j] = f2bf(r);
  }
}

// ---------------- fused message + bi-transform, layer 1 ----------------
// wave per node; 8 edges/iter; lane = (edge-slot g=lane>>3, dim-block q=lane&7)
__global__ void k_fused1(const float* __restrict__ ego1, const unsigned short* __restrict__ E1bf,
                         const float* __restrict__ attn,
                         const int* __restrict__ rowp, const int* __restrict__ srcs,
                         const float* __restrict__ W1, const float* __restrict__ b1,
                         const float* __restrict__ W2, const float* __restrict__ b2,
                         float* __restrict__ ego2) {
  __shared__ float wt1[4][36], wt2[4][36], bb[8];
  __shared__ float s1[4][4][36], s2[4][4][36];
  int t = threadIdx.x;
  if (t < 128) { int d = t >> 2, j = t & 3; wt1[j][d] = W1[t]; wt2[j][d] = W2[t]; }
  if (t < 4) bb[t] = b1[t];
  else if (t < 8) bb[t] = b2[t - 4];
  __syncthreads();
  int wv = t >> 6, lane = t & 63;
  int n = blockIdx.x * 4 + wv;
  int p0 = rowp[n], p1 = rowp[n + 1];
  int g = lane >> 3, q = lane & 7;
  float acc[4][4];
#pragma unroll
  for (int h = 0; h < 4; ++h)
#pragma unroll
    for (int j = 0; j < 4; ++j) acc[h][j] = 0.f;
  for (int p = p0 + g; p < p1; p += 8) {
    int s = srcs[p];
    float4 a = ((const float4*)attn)[p];
    ushort4 ev = *(const ushort4*)(E1bf + s * 32 + q * 4);
    float e0 = bf2f(ev.x), e1 = bf2f(ev.y), e2 = bf2f(ev.z), e3 = bf2f(ev.w);
    acc[0][0] += a.x * e0; acc[0][1] += a.x * e1; acc[0][2] += a.x * e2; acc[0][3] += a.x * e3;
    acc[1][0] += a.y * e0; acc[1][1] += a.y * e1; acc[1][2] += a.y * e2; acc[1][3] += a.y * e3;
    acc[2][0] += a.z * e0; acc[2][1] += a.z * e1; acc[2][2] += a.z * e2; acc[2][3] += a.z * e3;
    acc[3][0] += a.w * e0; acc[3][1] += a.w * e1; acc[3][2] += a.w * e2; acc[3][3] += a.w * e3;
  }
#pragma unroll
  for (int h = 0; h < 4; ++h)
#pragma unroll
    for (int j = 0; j < 4; ++j) {
      acc[h][j] += __shfl_xor(acc[h][j], 8);
      acc[h][j] += __shfl_xor(acc[h][j], 16);
      acc[h][j] += __shfl_xor(acc[h][j], 32);
    }
  if (lane < 8) {
    float4 e1v = *(const float4*)(ego1 + n * 32 + q * 4);
#pragma unroll
    for (int h = 0; h < 4; ++h) {
      float4 v1, v2;
      v1.x = e1v.x + acc[h][0]; v2.x = e1v.x * acc[h][0];
      v1.y = e1v.y + acc[h][1]; v2.y = e1v.y * acc[h][1];
      v1.z = e1v.z + acc[h][2]; v2.z = e1v.z * acc[h][2];
      v1.w = e1v.w + acc[h][3]; v2.w = e1v.w * acc[h][3];
      *(float4*)&s1[wv][h][q * 4] = v1;
      *(float4*)&s2[wv][h][q * 4] = v2;
    }
  }
  __syncthreads();
  if (lane < 32) {
    int h = (lane >> 2) & 3, j = lane & 3;
    const float* sp = (lane < 16) ? &s1[wv][h][0] : &s2[wv][h][0];
    const float* wp = (lane < 16) ? &wt1[j][0] : &wt2[j][0];
    float o = 0.f;
#pragma unroll
    for (int d = 0; d < 32; d += 4) {
      float4 sv = *(const float4*)(sp + d);
      float4 wv4 = *(const float4*)(wp + d);
      o += sv.x * wv4.x + sv.y * wv4.y + sv.z * wv4.z + sv.w * wv4.w;
    }
    o += (lane < 16) ? bb[j] : bb[4 + j];
    o = (o >= 0.f) ? o : 0.01f * o;
    float other = __shfl_xor(o, 16);
    if (lane < 16) ego2[n * 16 + h * 4 + j] = o + other;
  }
}

// ---------------- gather user/item rows with l2norm into U, V ----------------
__global__ void k_uv(const float* __restrict__ E, const float* __restrict__ E1,
                     const float* __restrict__ E2, const int* __restrict__ uid,
                     const int* __restrict__ iid, float* __restrict__ U,
                     float* __restrict__ V) {
  int row = (blockIdx.x * 256 + threadIdx.x) >> 6;
  int lane = threadIdx.x & 63;
  if (row >= 1000 + 4096) return;
  int id = (row < 1000) ? uid[row] : iid[row - 1000];
  float* dest = (row < 1000) ? (U + row * 112) : (V + (row - 1000) * 112);
  float v1 = (lane < 32) ? E1[id * 32 + lane] : 0.f;
  float s1 = v1 * v1;
  for (int m = 1; m < 64; m <<= 1) s1 += __shfl_xor(s1, m);
  float v2 = (lane < 16) ? E2[id * 16 + lane] : 0.f;
  float s2 = v2 * v2;
  for (int m = 1; m < 64; m <<= 1) s2 += __shfl_xor(s2, m);
  float i1 = 1.f / fmaxf(sqrtf(s1), 1e-12f);
  float i2 = 1.f / fmaxf(sqrtf(s2), 1e-12f);
  dest[lane] = E[id * 64 + lane];
  if (lane < 32) dest[64 + lane] = v1 * i1;
  if (lane < 16) dest[96 + lane] = v2 * i2;
}

// ---------------- final small GEMM: C[1000,4096] = U @ V^T (K=112) ----------------
__global__ void k_gemm(const float* __restrict__ U, const float* __restrict__ V,
                       float* __restrict__ C) {
  __shared__ float Us[16][113], Vs[16][113];
  int tx = threadIdx.x & 15, ty = threadIdx.x >> 4;
  int u0 = blockIdx.y * 16, v0 = blockIdx.x * 16;
  for (int i = threadIdx.x; i < 16 * 112; i += 256) {
    int rr = i / 112, cc = i % 112;
    int ur = u0 + rr;
    Us[rr][cc] = (ur < 1000) ? U[ur * 112 + cc] : 0.f;
    Vs[rr][cc] = V[(v0 + rr) * 112 + cc];
  }
  __syncthreads();
  int u = u0 + ty;
  if (u >= 1000) return;
  float acc = 0.f;
#pragma unroll
  for (int k = 0; k < 112; ++k) acc += Us[ty][k] * Vs[tx][k];
  C[u * 4096 + v0 + tx] = acc;
}

extern "C" void kernel_launch(void* const* d_in, const int* in_sizes, int n_in,
                              void* d_out, int out_size, void* d_ws, size_t ws_size,
                              hipStream_t stream) {
  const int* src = (const int*)d_in[0];
  const int* dst = (const int*)d_in[1];
  const int* etype = (const int*)d_in[2];
  const int* uid = (const int*)d_in[4];
  const int* iid = (const int*)d_in[5];
  const float* entity = (const float*)d_in[6];
  const float* rel = (const float*)d_in[7];
  const float* W_R = (const float*)d_in[8];
  const float* W_A = (const float*)d_in[9];
  const float* W1_0 = (const float*)d_in[10];
  const float* b1_0 = (const float*)d_in[11];
  const float* W2_0 = (const float*)d_in[12];
  const float* b2_0 = (const float*)d_in[13];
  const float* W1_1 = (const float*)d_in[14];
  const float* b1_1 = (const float*)d_in[15];
  const float* W2_1 = (const float*)d_in[16];
  const float* b2_1 = (const float*)d_in[17];
  float* out = (float*)d_out;

  char* ws = (char*)d_ws;
  // workspace layout (bytes); T1 region reused after k_att for layer outputs,
  // T2 region reused for normalized attention.
  unsigned char*  T1   = (unsigned char*) (ws + 0);            //  51,200,000
  float*          ego1 = (float*)         (ws + 0);            //  12,800,000 (alias T1)
  unsigned short* e1bf = (unsigned short*)(ws + 12800000);     //   6,400,000 (alias T1)
  float*          ego2 = (float*)         (ws + 19200000);     //   6,400,000 (alias T1)
  float*          U    = (float*)         (ws + 25600000);     //     448,000 (alias T1)
  float*          V    = (float*)         (ws + 26048000);     //   1,835,008 (alias T1)
  unsigned char*  T2   = (unsigned char*) (ws + 51200000);     //  51,200,000
  float*          attn = (float*)         (ws + 51200000);     //  25,600,000 (alias T2)
  float*          att  = (float*)         (ws + 102400000);    //  25,600,000
  int*            srcs = (int*)           (ws + 128000000);    //   6,400,000
  int*            ets  = (int*)           (ws + 134400000);    //   6,400,000
  int*            dsts = (int*)           (ws + 140800000);    //   6,400,000
  int*            rowp = (int*)           (ws + 147200000);    //     400,128
  int*            cnt  = (int*)           (ws + 147600128);    //     400,128
  int*            bsum = (int*)           (ws + 148000256);    //         512
  unsigned short* Wbf  = (unsigned short*)(ws + 148000768);    //      65,536
  float*          rea  = (float*)         (ws + 148066304);    //       2,048
  unsigned short* Ebf  = (unsigned short*)(ws + 148068352);    //  12,800,000
  float*          minv = (float*)         (ws + 160868352);    //   3,200,000
  // total: 164,068,352 bytes

  hipMemsetAsync(cnt, 0, NN * sizeof(int), stream);
  k_prep<<<130, 256, 0, stream>>>(W_R, W_A, rel, Wbf, rea);
  k_cvt<<<6250, 256, 0, stream>>>(entity, Ebf);
  k_proj<<<(NN + 63) / 64, 256, 0, stream>>>(Ebf, Wbf, rea, T1, T2);
  k_hist<<<NE / 256, 256, 0, stream>>>(dst, cnt);
  k_scan1<<<NSCAN, SCAN_B, 0, stream>>>(cnt, rowp, bsum);
  k_scan2<<<1, 64, 0, stream>>>(bsum);
  k_scan3<<<NSCAN, SCAN_B, 0, stream>>>(rowp, bsum);
  hipMemsetAsync(cnt, 0, NN * sizeof(int), stream);
  k_scatter<<<NE / 256, 256, 0, stream>>>(src, dst, etype, rowp, cnt, srcs, ets, dsts);
  k_att<<<NE * 4 / 256, 256, 0, stream>>>(T1, T2, srcs, dsts, ets, att);
  k_nodemax<<<(NN * 4 + 255) / 256, 256, 0, stream>>>(rowp, att, minv);
  k_attn<<<NE * 4 / 256, 256, 0, stream>>>(att, minv, dsts, attn);
  k_fused0<<<NN / 4, 256, 0, stream>>>(entity, Ebf, attn, rowp, srcs,
                                       W1_0, b1_0, W2_0, b2_0, ego1, e1bf);
  k_fused1<<<NN / 4, 256, 0, stream>>>(ego1, e1bf, attn, rowp, srcs,
                                       W1_1, b1_1, W2_1, b2_1, ego2);
  k_uv<<<(1000 + 4096 + 3) / 4, 256, 0, stream>>>(entity, ego1, ego2, uid, iid, U, V);
  k_gemm<<<dim3(4096 / 16, (1000 + 15) / 16), 256, 0, stream>>>(U, V, out);
}